// Round 5
// baseline (439.940 us; speedup 1.0000x reference)
//
#include <hip/hip_runtime.h>
#include <stdint.h>

typedef unsigned short ushort_t;
typedef __attribute__((ext_vector_type(8))) __bf16 bf16x8;
typedef __attribute__((ext_vector_type(4))) float f32x4;

#define HIDDEN 2048
#define NHEADS 16
#define HDIM 128
#define SEQ 2048
#define BATCH 2
#define MROWS (BATCH*SEQ)

#define AS1 __attribute__((address_space(1)))
#define AS3 __attribute__((address_space(3)))

__device__ __forceinline__ ushort_t f2bf(float f) {
  uint32_t u = __float_as_uint(f);
  u += 0x7FFFu + ((u >> 16) & 1u);
  return (ushort_t)(u >> 16);
}
__device__ __forceinline__ float bf2f(ushort_t h) {
  return __uint_as_float((uint32_t)h << 16);
}

__device__ __forceinline__ f32x4 mfma16(bf16x8 a, bf16x8 b, f32x4 c) {
  return __builtin_amdgcn_mfma_f32_16x16x32_bf16(a, b, c, 0, 0, 0);
}

// ---------------- fp32 -> bf16 converts ----------------
__global__ void cvt_kernel(const float* __restrict__ in, ushort_t* __restrict__ out, int n4) {
  int i = blockIdx.x * blockDim.x + threadIdx.x;
  if (i < n4) {
    float4 v = ((const float4*)in)[i];
    uint32_t lo = (uint32_t)f2bf(v.x) | ((uint32_t)f2bf(v.y) << 16);
    uint32_t hi = (uint32_t)f2bf(v.z) | ((uint32_t)f2bf(v.w) << 16);
    ((uint2*)out)[i] = make_uint2(lo, hi);
  }
}

__global__ void cvt4_kernel(const float* __restrict__ w0, const float* __restrict__ w1,
                            const float* __restrict__ w2, const float* __restrict__ w3,
                            ushort_t* __restrict__ o0, ushort_t* __restrict__ o1,
                            ushort_t* __restrict__ o2, ushort_t* __restrict__ o3) {
  int y = blockIdx.y;
  const float* in = (y == 0) ? w0 : (y == 1) ? w1 : (y == 2) ? w2 : w3;
  ushort_t* out = (y == 0) ? o0 : (y == 1) ? o1 : (y == 2) ? o2 : o3;
  int i = blockIdx.x * blockDim.x + threadIdx.x;
  float4 v = ((const float4*)in)[i];
  uint32_t lo = (uint32_t)f2bf(v.x) | ((uint32_t)f2bf(v.y) << 16);
  uint32_t hi = (uint32_t)f2bf(v.z) | ((uint32_t)f2bf(v.w) << 16);
  ((uint2*)out)[i] = make_uint2(lo, hi);
}

// ------- 128x128x2048 GEMM core (kept for out_gemm) -------
__device__ __forceinline__ void gemm128_core(const ushort_t* __restrict__ Ag,
                                             const ushort_t* __restrict__ Bg,
                                             ushort_t* As, ushort_t* Bs,  // each 2*4096
                                             f32x4 acc[4][4], int tid) {
  const int lane = tid & 63, wv = tid >> 6;
  const int r4 = lane >> 2;
  const int c8 = (((lane & 3) ^ ((r4 >> 1) & 3)) << 3);
  const int wm = (wv >> 1) * 64, wn = (wv & 1) * 64;
  const int mq = lane & 15, quad = lane >> 4;
  const int sw = (mq >> 1) & 3;

  auto stage = [&](int k0, int buf) {
#pragma unroll
    for (int cc = 0; cc < 2; ++cc) {
      int chunk = wv + cc * 4;
      const ushort_t* ga = Ag + (size_t)(chunk * 16 + r4) * HIDDEN + k0 + c8;
      const ushort_t* gb = Bg + (size_t)(chunk * 16 + r4) * HIDDEN + k0 + c8;
      __builtin_amdgcn_global_load_lds((AS1 void*)ga, (AS3 void*)(As + buf * 4096 + chunk * 512), 16, 0, 0);
      __builtin_amdgcn_global_load_lds((AS1 void*)gb, (AS3 void*)(Bs + buf * 4096 + chunk * 512), 16, 0, 0);
    }
  };

  stage(0, 0);
  __syncthreads();
#pragma unroll 1
  for (int k0 = 0; k0 < HIDDEN; k0 += 32) {
    const int cur = (k0 >> 5) & 1;
    if (k0 + 32 < HIDDEN) stage(k0 + 32, cur ^ 1);
    const ushort_t* A = As + cur * 4096;
    const ushort_t* B = Bs + cur * 4096;
    bf16x8 a[4], b[4];
#pragma unroll
    for (int i = 0; i < 4; ++i)
      a[i] = *(const bf16x8*)(A + (wm + i * 16 + mq) * 32 + ((quad ^ sw) << 3));
#pragma unroll
    for (int j = 0; j < 4; ++j)
      b[j] = *(const bf16x8*)(B + (wn + j * 16 + mq) * 32 + ((quad ^ sw) << 3));
#pragma unroll
    for (int i = 0; i < 4; ++i)
#pragma unroll
      for (int j = 0; j < 4; ++j)
        acc[i][j] = mfma16(a[i], b[j], acc[i][j]);
    __syncthreads();
  }
}

// ================= fused QKV projection: 256x256 tile, 8-wave, 8-phase =================
// (R2-measured version: 131.6 us, MfmaUtil 32%, bank-conflict ~0. Proven pass.)
// Tile: BM=BN=256, BK=64. LDS: 2 buf x [A0|A1|B0|B1] halves (128x64 bf16 each) = 128 KiB.
// Swizzle: 16B granule g stored at g ^ (row&7) (pre-swizzled global src + swizzled ds_read).
// vmcnt ledger (2 loads/half): gates vmcnt(4) at end of P1/P2/P4 -> each consumed half landed
// >=2 phases after issue; 4-8 loads always in flight (never drains to 0 in main loop).

#define QKV_PHASE_MFMA(MH, NH, BB)                                                  \
  __builtin_amdgcn_s_barrier();                                                     \
  asm volatile("s_waitcnt lgkmcnt(0)" ::: "memory");                                \
  __builtin_amdgcn_s_setprio(1);                                                    \
  _Pragma("unroll") for (int f_ = 0; f_ < 4; ++f_)                                  \
  _Pragma("unroll") for (int n_ = 0; n_ < 2; ++n_)                                  \
  _Pragma("unroll") for (int kk_ = 0; kk_ < 2; ++kk_)                               \
    acc[(MH)*4+f_][(NH)*2+n_] =                                                     \
      mfma16(af[f_*2+kk_], BB[n_*2+kk_], acc[(MH)*4+f_][(NH)*2+n_]);                \
  __builtin_amdgcn_s_setprio(0);

#define QKV_TILE(CB, NB, KT)                                                        \
  {                                                                                 \
    const ushort_t* A_ = lds_q + (CB);                                              \
    const ushort_t* B_ = lds_q + (CB) + 16384;                                      \
    _Pragma("unroll") for (int u = 0; u < 8; ++u) af[u] = *(const bf16x8*)(A_ + aoff[u]); \
    _Pragma("unroll") for (int u = 0; u < 4; ++u) b0r[u] = *(const bf16x8*)(B_ + boff[u]); \
    stageA((KT), 0, (NB));                                                          \
    QKV_PHASE_MFMA(0, 0, b0r)                                                       \
    asm volatile("s_waitcnt vmcnt(4)" ::: "memory");                                \
    __builtin_amdgcn_s_barrier();                                                   \
    _Pragma("unroll") for (int u = 0; u < 4; ++u) b1r[u] = *(const bf16x8*)(B_ + 8192 + boff[u]); \
    stageB((KT), 0, (NB));                                                          \
    QKV_PHASE_MFMA(0, 1, b1r)                                                       \
    asm volatile("s_waitcnt vmcnt(4)" ::: "memory");                                \
    __builtin_amdgcn_s_barrier();                                                   \
    _Pragma("unroll") for (int u = 0; u < 8; ++u) af[u] = *(const bf16x8*)(A_ + 8192 + aoff[u]); \
    stageB((KT), 1, (NB));                                                          \
    QKV_PHASE_MFMA(1, 1, b1r)                                                       \
    __builtin_amdgcn_s_barrier();                                                   \
    stageA((KT), 1, (NB));                                                          \
    QKV_PHASE_MFMA(1, 0, b0r)                                                       \
    asm volatile("s_waitcnt vmcnt(4)" ::: "memory");                                \
    __builtin_amdgcn_s_barrier();                                                   \
  }

#define QKV_TAIL(CB)                                                                \
  {                                                                                 \
    const ushort_t* A_ = lds_q + (CB);                                              \
    const ushort_t* B_ = lds_q + (CB) + 16384;                                      \
    _Pragma("unroll") for (int u = 0; u < 8; ++u) af[u] = *(const bf16x8*)(A_ + aoff[u]); \
    _Pragma("unroll") for (int u = 0; u < 4; ++u) b0r[u] = *(const bf16x8*)(B_ + boff[u]); \
    QKV_PHASE_MFMA(0, 0, b0r)                                                       \
    asm volatile("s_waitcnt vmcnt(2)" ::: "memory");                                \
    __builtin_amdgcn_s_barrier();                                                   \
    _Pragma("unroll") for (int u = 0; u < 4; ++u) b1r[u] = *(const bf16x8*)(B_ + 8192 + boff[u]); \
    QKV_PHASE_MFMA(0, 1, b1r)                                                       \
    asm volatile("s_waitcnt vmcnt(0)" ::: "memory");                                \
    __builtin_amdgcn_s_barrier();                                                   \
    _Pragma("unroll") for (int u = 0; u < 8; ++u) af[u] = *(const bf16x8*)(A_ + 8192 + aoff[u]); \
    QKV_PHASE_MFMA(1, 1, b1r)                                                       \
    __builtin_amdgcn_s_barrier();                                                   \
    QKV_PHASE_MFMA(1, 0, b0r)                                                       \
  }

__global__ __launch_bounds__(512, 2) void qkv_gemm(const ushort_t* __restrict__ X,
                                                   const ushort_t* __restrict__ Wq,
                                                   const ushort_t* __restrict__ Wk,
                                                   const ushort_t* __restrict__ Wv,
                                                   ushort_t* __restrict__ Q,
                                                   ushort_t* __restrict__ K,
                                                   ushort_t* __restrict__ Vt) {
  __shared__ __align__(16) ushort_t lds_q[65536];   // 128 KiB

  const int tid = threadIdx.x, lane = tid & 63, wv = tid >> 6;
  const int wr = wv >> 2, wc = wv & 3;
  const int mq = lane & 15, quad = lane >> 4;
  const int lr = lane >> 3;
  const int csw = ((lane & 7) ^ (lr & 7)) * 8;      // pre-swizzled source col (elems)

  // block mapping: 384 blocks, XCD gets 3 consecutive N-panels (3 MB, L2-resident)
  const int lin = blockIdx.x;
  const int xcd = lin & 7, s = lin >> 3;            // s in [0,48)
  const int by = xcd * 3 + (s % 3);                 // 24 N-tiles
  const int bx = s / 3;                             // 16 M-tiles
  const int m0 = bx * 256;
  const int nglob = by * 256;
  const int which = nglob >> 11;
  const int n0 = nglob & 2047;
  const ushort_t* Ag = X + (size_t)m0 * HIDDEN;
  const ushort_t* Bg = ((which == 0) ? Wq : (which == 1) ? Wk : Wv) + (size_t)n0 * HIDDEN;

  // LDS read offsets (elems). Fragment interleave: wave wr owns M rows {f*32 + wr*16 + mq},
  // wave wc owns N cols {n*64 + wc*16 + mq} -> phase (mh,nh) touches exactly half (mh)/(nh).
  int aoff[8], boff[4];
#pragma unroll
  for (int f = 0; f < 4; ++f)
#pragma unroll
    for (int kk = 0; kk < 2; ++kk)
      aoff[f * 2 + kk] = (f * 32 + wr * 16 + mq) * 64 + (((kk * 4 + quad) ^ (mq & 7)) * 8);
#pragma unroll
  for (int n = 0; n < 2; ++n)
#pragma unroll
    for (int kk = 0; kk < 2; ++kk)
      boff[n * 2 + kk] = (n * 64 + wc * 16 + mq) * 64 + (((kk * 4 + quad) ^ (mq & 7)) * 8);

  auto stageA = [&](int kt, int half, int nb) {
#pragma unroll
    for (int i = 0; i < 2; ++i) {
      int seg = wv + i * 8;
      const ushort_t* src = Ag + (size_t)(half * 128 + seg * 8 + lr) * HIDDEN + kt * 64 + csw;
      __builtin_amdgcn_global_load_lds((AS1 void*)src,
                                       (AS3 void*)(lds_q + nb + half * 8192 + seg * 512), 16, 0, 0);
    }
  };
  auto stageB = [&](int kt, int half, int nb) {
#pragma unroll
    for (int i = 0; i < 2; ++i) {
      int seg = wv + i * 8;
      const ushort_t* src = Bg + (size_t)(half * 128 + seg * 8 + lr) * HIDDEN + kt * 64 + csw;
      __builtin_amdgcn_global_load_lds((AS1 void*)src,
                                       (AS3 void*)(lds_q + nb + 16384 + half * 8192 + seg * 512), 16, 0, 0);
    }
  };

  f32x4 acc[8][4];
  const f32x4 zf = {0.f, 0.f, 0.f, 0.f};
#pragma unroll
  for (int i = 0; i < 8; ++i)
#pragma unroll
    for (int j = 0; j < 4; ++j) acc[i][j] = zf;

  bf16x8 af[8], b0r[4], b1r[4];

  // prologue: tile 0, issue order == consumption order (A0,B0,B1,A1)
  stageA(0, 0, 0);
  stageB(0, 0, 0);
  stageB(0, 1, 0);
  stageA(0, 1, 0);
  __syncthreads();

#pragma unroll 1
  for (int tp = 0; tp < 15; ++tp) {
    QKV_TILE(0, 32768, 2 * tp + 1)
    QKV_TILE(32768, 0, 2 * tp + 2)
  }
  QKV_TILE(0, 32768, 31)
  QKV_TAIL(32768)

  // -------- epilogue --------
  // acc[a][c]: M row = m0 + (a>>2)*128 + (a&3)*32 + wr*16 + quad*4 + r
  //            N col = n0 + (c>>1)*128 + (c&1)*64 + wc*16 + mq
  if (which != 2) {
    ushort_t* dst = (which == 0) ? Q : K;
#pragma unroll
    for (int a = 0; a < 8; ++a)
#pragma unroll
      for (int c = 0; c < 4; ++c)
#pragma unroll
        for (int r = 0; r < 4; ++r) {
          int mrow = m0 + (a >> 2) * 128 + (a & 3) * 32 + wr * 16 + quad * 4 + r;
          int ocol = n0 + (c >> 1) * 128 + (c & 1) * 64 + wc * 16 + mq;
          int bb = mrow >> 11, sq = mrow & (SEQ - 1);
          int hh = ocol >> 7, d = ocol & (HDIM - 1);
          dst[((size_t)(bb * NHEADS + hh) * SEQ + sq) * HDIM + d] = f2bf(acc[a][c][r]);
        }
  } else {
    // V: transpose 256x256 through the full staging LDS -> coalesced uint4 stores to Vt
    __syncthreads();
#pragma unroll
    for (int a = 0; a < 8; ++a)
#pragma unroll
      for (int c4 = 0; c4 < 4; ++c4) {
        int cc = (c4 >> 1) * 128 + (c4 & 1) * 64 + wc * 16 + mq;
        int mb = (a >> 2) * 128 + (a & 3) * 32 + wr * 16 + quad * 4;
        uint32_t lo = (uint32_t)f2bf(acc[a][c4][0]) | ((uint32_t)f2bf(acc[a][c4][1]) << 16);
        uint32_t hi = (uint32_t)f2bf(acc[a][c4][2]) | ((uint32_t)f2bf(acc[a][c4][3]) << 16);
        *(uint2*)(lds_q + cc * 256 + (mb ^ ((cc & 7) * 8))) = make_uint2(lo, hi);
      }
    __syncthreads();
    const int bb = m0 >> 11, sq0 = m0 & (SEQ - 1);
#pragma unroll
    for (int it = 0; it < 16; ++it) {
      int cc = it * 16 + (tid >> 5);
      int sc = tid & 31;
      uint4 v = *(const uint4*)(lds_q + cc * 256 + ((sc ^ (cc & 7)) * 8));
      int hh = (n0 + cc) >> 7, d = (n0 + cc) & (HDIM - 1);
      *(uint4*)(Vt + ((size_t)(bb * NHEADS + hh) * HDIM + d) * SEQ + sq0 + sc * 8) = v;
    }
  }
}

// ---------------- RoPE over Q and K (1/sqrt(d) folded into Q) ----------------
__global__ void rope_kernel(ushort_t* __restrict__ Q, ushort_t* __restrict__ K) {
  int i = blockIdx.x * blockDim.x + threadIdx.x;
  int d = i & 63;
  int s = (i >> 6) & (SEQ - 1);
  int bh = i >> 17;
  size_t base = ((size_t)bh * SEQ + s) * HDIM;
  float inv = exp2f((float)d * -0.2076205059304601f);
  float ang = (float)s * inv;
  float sn, cs;
  sincosf(ang, &sn, &cs);
  const float scale = 0.08838834764831845f;
  float q0 = bf2f(Q[base + d]), q1 = bf2f(Q[base + d + 64]);
  Q[base + d]      = f2bf((q0 * cs - q1 * sn) * scale);
  Q[base + d + 64] = f2bf((q1 * cs + q0 * sn) * scale);
  float k0 = bf2f(K[base + d]), k1 = bf2f(K[base + d + 64]);
  K[base + d]      = f2bf(k0 * cs - k1 * sn);
  K[base + d + 64] = f2bf(k1 * cs + k0 * sn);
}

// ---- causal flash attention: ONE Q-tile per block, 2 blocks/CU co-resident ----
// Grid 512 = 32 bh x 16 T. LDS exactly 80KB -> two blocks fit in a CU's 160KB;
// one block's MFMA overlaps the other's softmax VALU (2 waves/SIMD). Inner loop
// is byte-identical to the R2-passing pair version; only T mapping changed.
__global__ __launch_bounds__(256, 1) void flash_kernel(const ushort_t* __restrict__ Q,
                                                       const ushort_t* __restrict__ K,
                                                       const ushort_t* __restrict__ Vt,
                                                       ushort_t* __restrict__ Ao) {
  __shared__ __align__(16) ushort_t sK[2][64 * 128];   // keys: 64 rows x 128 d (32KB)
  __shared__ __align__(16) ushort_t sV[2][128 * 64];   // V^T: 128 d x 64 keys (32KB)
  __shared__ __align__(16) ushort_t sP[128 * 64];      // P^T as [q][key] (16KB)
  ushort_t* sO = &sK[0][0];                            // 128x128 epilogue scratch (32KB)

  const int tid = threadIdx.x, lane = tid & 63, wv = tid >> 6;
  const int lq = lane & 15, quad = lane >> 4;
  const int lin = blockIdx.x;
  const int xcd = lin & 7, slot = lin >> 3;            // slot in [0,64)
  const int bh = xcd * 4 + (slot & 3);
  const int T = slot >> 2;                             // 0..15
  const ushort_t* Qb = Q + (size_t)bh * SEQ * HDIM;
  const ushort_t* Kb = K + (size_t)bh * SEQ * HDIM;
  const ushort_t* Vb = Vt + (size_t)bh * HDIM * SEQ;
  const int b = bh >> 4, h = bh & 15;

  auto stageK = [&](int j, ushort_t* dst) {
    int rr = lane >> 4, g = lane & 15;
#pragma unroll
    for (int t = 0; t < 4; ++t) {
      int chunk = wv * 4 + t;
      int row = chunk * 4 + rr;
      int gs = (g ^ (row & 7)) * 8;
      __builtin_amdgcn_global_load_lds((AS1 void*)(Kb + (size_t)(j * 64 + row) * HDIM + gs),
                                       (AS3 void*)(dst + chunk * 512), 16, 0, 0);
    }
  };
  auto stageV = [&](int j, ushort_t* dst) {
    int rr = lane >> 3, g = lane & 7;
#pragma unroll
    for (int t = 0; t < 4; ++t) {
      int chunk = wv * 4 + t;
      int row = chunk * 8 + rr;
      int gs = (g ^ (row & 7)) * 8;
      __builtin_amdgcn_global_load_lds((AS1 void*)(Vb + (size_t)row * SEQ + j * 64 + gs),
                                       (AS3 void*)(dst + chunk * 512), 16, 0, 0);
    }
  };

  const f32x4 zf = {0.f, 0.f, 0.f, 0.f};
  const int nsteps = 2 * T + 2;

  bf16x8 qf[2][4];
#pragma unroll
  for (int n = 0; n < 2; ++n)
#pragma unroll
    for (int kt = 0; kt < 4; ++kt)
      qf[n][kt] = *(const bf16x8*)(Qb + (size_t)(T * 128 + wv * 32 + n * 16 + lq) * HDIM +
                                   kt * 32 + quad * 8);

  float m_i[2] = {-1e30f, -1e30f}, l_i[2] = {0.f, 0.f};
  f32x4 oacc[8][2];
#pragma unroll
  for (int m = 0; m < 8; ++m)
#pragma unroll
    for (int n = 0; n < 2; ++n) oacc[m][n] = zf;

  stageK(0, sK[0]);
  stageV(0, sV[0]);
  __syncthreads();

#pragma unroll 1
  for (int j = 0; j < nsteps; ++j) {
    const int cur = j & 1;
    if (j + 1 < nsteps) {
      stageK(j + 1, sK[cur ^ 1]);
      stageV(j + 1, sV[cur ^ 1]);
    }

    const ushort_t* sKc = sK[cur];
    f32x4 sacc[4][2];
#pragma unroll
    for (int m = 0; m < 4; ++m)
#pragma unroll
      for (int n = 0; n < 2; ++n) sacc[m][n] = zf;
#pragma unroll
    for (int kt = 0; kt < 4; ++kt) {
      bf16x8 kf[4];
#pragma unroll
      for (int m = 0; m < 4; ++m) {
        int row = m * 16 + lq;
        kf[m] = *(const bf16x8*)(sKc + row * 128 + (((kt * 4 + quad) ^ (row & 7)) * 8));
      }
#pragma unroll
      for (int m = 0; m < 4; ++m)
#pragma unroll
        for (int n = 0; n < 2; ++n)
          sacc[m][n] = mfma16(kf[m], qf[n][kt], sacc[m][n]);
    }

    const bool diag = (j >= 2 * T);
#pragma unroll
    for (int n = 0; n < 2; ++n) {
      const int qr = wv * 32 + n * 16 + lq;
      if (diag) {
        const int rowg = T * 128 + qr;
#pragma unroll
        for (int m = 0; m < 4; ++m)
#pragma unroll
          for (int r = 0; r < 4; ++r) {
            int key = j * 64 + m * 16 + quad * 4 + r;
            if (key > rowg) sacc[m][n][r] = -1e30f;
          }
      }
      float rm = -1e30f;
#pragma unroll
      for (int m = 0; m < 4; ++m)
#pragma unroll
        for (int r = 0; r < 4; ++r) rm = fmaxf(rm, sacc[m][n][r]);
      rm = fmaxf(rm, __shfl_xor(rm, 16, 64));
      rm = fmaxf(rm, __shfl_xor(rm, 32, 64));
      float mnew = fmaxf(m_i[n], rm);
      float alpha = __expf(m_i[n] - mnew);
      m_i[n] = mnew;
      float rs = 0.f;
#pragma unroll
      for (int m = 0; m < 4; ++m)
#pragma unroll
        for (int r = 0; r < 4; ++r) {
          float p = __expf(sacc[m][n][r] - mnew);
          sacc[m][n][r] = p;
          rs += p;
        }
      rs += __shfl_xor(rs, 16, 64);
      rs += __shfl_xor(rs, 32, 64);
      l_i[n] = l_i[n] * alpha + rs;
#pragma unroll
      for (int m = 0; m < 8; ++m)
#pragma unroll
        for (int r = 0; r < 4; ++r) oacc[m][n][r] *= alpha;
#pragma unroll
      for (int m = 0; m < 4; ++m) {
        uint32_t lo = (uint32_t)f2bf(sacc[m][n][0]) | ((uint32_t)f2bf(sacc[m][n][1]) << 16);
        uint32_t hi = (uint32_t)f2bf(sacc[m][n][2]) | ((uint32_t)f2bf(sacc[m][n][3]) << 16);
        int gw = m * 2 + (quad >> 1);
        *(uint2*)(sP + qr * 64 + ((gw ^ (qr & 7)) * 8) + (quad & 1) * 4) = make_uint2(lo, hi);
      }
    }

    const ushort_t* sVc = sV[cur];
#pragma unroll
    for (int kt = 0; kt < 2; ++kt) {
      bf16x8 pf[2];
#pragma unroll
      for (int n = 0; n < 2; ++n) {
        int qr = wv * 32 + n * 16 + lq;
        pf[n] = *(const bf16x8*)(sP + qr * 64 + (((kt * 4 + quad) ^ (qr & 7)) * 8));
      }
#pragma unroll
      for (int m = 0; m < 8; ++m) {
        int d = m * 16 + lq;
        bf16x8 vf = *(const bf16x8*)(sVc + d * 64 + (((kt * 4 + quad) ^ (d & 7)) * 8));
#pragma unroll
        for (int n = 0; n < 2; ++n)
          oacc[m][n] = mfma16(vf, pf[n], oacc[m][n]);
      }
    }

    __syncthreads();
  }

  float inv0 = 1.f / l_i[0], inv1 = 1.f / l_i[1];
#pragma unroll
  for (int n = 0; n < 2; ++n) {
    float inv = n ? inv1 : inv0;
    int qr = wv * 32 + n * 16 + lq;
#pragma unroll
    for (int m = 0; m < 8; ++m) {
      uint32_t lo = (uint32_t)f2bf(oacc[m][n][0] * inv) | ((uint32_t)f2bf(oacc[m][n][1] * inv) << 16);
      uint32_t hi = (uint32_t)f2bf(oacc[m][n][2] * inv) | ((uint32_t)f2bf(oacc[m][n][3] * inv) << 16);
      int gw = m * 2 + (quad >> 1);
      *(uint2*)(sO + qr * 128 + ((gw ^ (qr & 7)) * 8) + (quad & 1) * 4) = make_uint2(lo, hi);
    }
  }
  __syncthreads();
#pragma unroll
  for (int it = 0; it < 8; ++it) {
    int qr = it * 16 + (tid >> 4);
    int g = tid & 15;
    uint4 v = *(const uint4*)(sO + qr * 128 + ((g ^ (qr & 7)) * 8));
    *(uint4*)(Ao + ((size_t)(b * SEQ + T * 128 + qr)) * (NHEADS * HDIM) + h * HDIM + g * 8) = v;
  }
}

// ---------------- output projection (fp32 out, XCD-swizzled) ----------------
__global__ __launch_bounds__(256) void out_gemm(const ushort_t* __restrict__ Ain,
                                                const ushort_t* __restrict__ Wo,
                                                float* __restrict__ Y) {
  __shared__ __align__(16) ushort_t As[2][128 * 32];
  __shared__ __align__(16) ushort_t Bs[2][128 * 32];
  const int tid = threadIdx.x;
  const int lin = blockIdx.x;
  const int xcd = lin & 7, s = lin >> 3;
  const int by = xcd + 8 * (s & 1);
  const int bx = s >> 1;
  const int m0 = bx * 128;
  const int n0 = by * 128;

  f32x4 acc[4][4];
  const f32x4 zf = {0.f, 0.f, 0.f, 0.f};
#pragma unroll
  for (int i = 0; i < 4; ++i)
#pragma unroll
    for (int j = 0; j < 4; ++j) acc[i][j] = zf;

  gemm128_core(Ain + (size_t)m0 * HIDDEN, Wo + (size_t)n0 * HIDDEN, &As[0][0], &Bs[0][0], acc, tid);

  const int lane = tid & 63, wv = tid >> 6;
  const int wm = (wv >> 1) * 64, wn = (wv & 1) * 64;
  const int mq = lane & 15, quad = lane >> 4;
#pragma unroll
  for (int i = 0; i < 4; ++i)
#pragma unroll
    for (int j = 0; j < 4; ++j)
#pragma unroll
      for (int r = 0; r < 4; ++r) {
        int m = m0 + wm + i * 16 + quad * 4 + r;
        int o = n0 + wn + j * 16 + mq;
        Y[(size_t)m * HIDDEN + o] = acc[i][j][r];
      }
}

extern "C" void kernel_launch(void* const* d_in, const int* in_sizes, int n_in,
                              void* d_out, int out_size, void* d_ws, size_t ws_size,
                              hipStream_t stream) {
  const float* hs = (const float*)d_in[0];
  const float* Wq = (const float*)d_in[1];
  const float* Wk = (const float*)d_in[2];
  const float* Wv = (const float*)d_in[3];
  const float* Wo = (const float*)d_in[4];
  float* out = (float*)d_out;

  ushort_t* ws  = (ushort_t*)d_ws;
  ushort_t* Xb  = ws;
  ushort_t* Wqb = Xb  + (size_t)MROWS * HIDDEN;
  ushort_t* Wkb = Wqb + (size_t)HIDDEN * HIDDEN;
  ushort_t* Wvb = Wkb + (size_t)HIDDEN * HIDDEN;
  ushort_t* Wob = Wvb + (size_t)HIDDEN * HIDDEN;
  ushort_t* Qb  = Wob + (size_t)HIDDEN * HIDDEN;
  ushort_t* Kb  = Qb  + (size_t)MROWS * HIDDEN;
  ushort_t* Vtb = Kb  + (size_t)MROWS * HIDDEN;
  ushort_t* Ao  = Vtb + (size_t)MROWS * HIDDEN;

  cvt_kernel<<<(MROWS * HIDDEN / 4) / 256, 256, 0, stream>>>(hs, Xb, MROWS * HIDDEN / 4);
  cvt4_kernel<<<dim3((HIDDEN * HIDDEN / 4) / 256, 4), 256, 0, stream>>>(
      Wq, Wk, Wv, Wo, Wqb, Wkb, Wvb, Wob);

  qkv_gemm<<<dim3(384), 512, 0, stream>>>(Xb, Wqb, Wkb, Wvb, Qb, Kb, Vtb);
  rope_kernel<<<(BATCH * NHEADS * SEQ * 64) / 256, 256, 0, stream>>>(Qb, Kb);
  flash_kernel<<<dim3(512), 256, 0, stream>>>(Qb, Kb, Vtb, Ao);
  out_gemm<<<dim3(512), 256, 0, stream>>>(Ao, Wob, out);
}

// Round 6
// 414.234 us; speedup vs baseline: 1.0621x; 1.0621x over previous
//
#include <hip/hip_runtime.h>
#include <stdint.h>

typedef unsigned short ushort_t;
typedef __attribute__((ext_vector_type(8))) __bf16 bf16x8;
typedef __attribute__((ext_vector_type(4))) float f32x4;

#define HIDDEN 2048
#define NHEADS 16
#define HDIM 128
#define SEQ 2048
#define BATCH 2
#define MROWS (BATCH*SEQ)

#define AS1 __attribute__((address_space(1)))
#define AS3 __attribute__((address_space(3)))

__device__ __forceinline__ ushort_t f2bf(float f) {
  uint32_t u = __float_as_uint(f);
  u += 0x7FFFu + ((u >> 16) & 1u);
  return (ushort_t)(u >> 16);
}
__device__ __forceinline__ float bf2f(ushort_t h) {
  return __uint_as_float((uint32_t)h << 16);
}

__device__ __forceinline__ f32x4 mfma16(bf16x8 a, bf16x8 b, f32x4 c) {
  return __builtin_amdgcn_mfma_f32_16x16x32_bf16(a, b, c, 0, 0, 0);
}

// ---------------- fp32 -> bf16 converts ----------------
__global__ void cvt_kernel(const float* __restrict__ in, ushort_t* __restrict__ out, int n4) {
  int i = blockIdx.x * blockDim.x + threadIdx.x;
  if (i < n4) {
    float4 v = ((const float4*)in)[i];
    uint32_t lo = (uint32_t)f2bf(v.x) | ((uint32_t)f2bf(v.y) << 16);
    uint32_t hi = (uint32_t)f2bf(v.z) | ((uint32_t)f2bf(v.w) << 16);
    ((uint2*)out)[i] = make_uint2(lo, hi);
  }
}

__global__ void cvt4_kernel(const float* __restrict__ w0, const float* __restrict__ w1,
                            const float* __restrict__ w2, const float* __restrict__ w3,
                            ushort_t* __restrict__ o0, ushort_t* __restrict__ o1,
                            ushort_t* __restrict__ o2, ushort_t* __restrict__ o3) {
  int y = blockIdx.y;
  const float* in = (y == 0) ? w0 : (y == 1) ? w1 : (y == 2) ? w2 : w3;
  ushort_t* out = (y == 0) ? o0 : (y == 1) ? o1 : (y == 2) ? o2 : o3;
  int i = blockIdx.x * blockDim.x + threadIdx.x;
  float4 v = ((const float4*)in)[i];
  uint32_t lo = (uint32_t)f2bf(v.x) | ((uint32_t)f2bf(v.y) << 16);
  uint32_t hi = (uint32_t)f2bf(v.z) | ((uint32_t)f2bf(v.w) << 16);
  ((uint2*)out)[i] = make_uint2(lo, hi);
}

// ------- 128x128x2048 GEMM core (kept for out_gemm) -------
__device__ __forceinline__ void gemm128_core(const ushort_t* __restrict__ Ag,
                                             const ushort_t* __restrict__ Bg,
                                             ushort_t* As, ushort_t* Bs,  // each 2*4096
                                             f32x4 acc[4][4], int tid) {
  const int lane = tid & 63, wv = tid >> 6;
  const int r4 = lane >> 2;
  const int c8 = (((lane & 3) ^ ((r4 >> 1) & 3)) << 3);
  const int wm = (wv >> 1) * 64, wn = (wv & 1) * 64;
  const int mq = lane & 15, quad = lane >> 4;
  const int sw = (mq >> 1) & 3;

  auto stage = [&](int k0, int buf) {
#pragma unroll
    for (int cc = 0; cc < 2; ++cc) {
      int chunk = wv + cc * 4;
      const ushort_t* ga = Ag + (size_t)(chunk * 16 + r4) * HIDDEN + k0 + c8;
      const ushort_t* gb = Bg + (size_t)(chunk * 16 + r4) * HIDDEN + k0 + c8;
      __builtin_amdgcn_global_load_lds((AS1 void*)ga, (AS3 void*)(As + buf * 4096 + chunk * 512), 16, 0, 0);
      __builtin_amdgcn_global_load_lds((AS1 void*)gb, (AS3 void*)(Bs + buf * 4096 + chunk * 512), 16, 0, 0);
    }
  };

  stage(0, 0);
  __syncthreads();
#pragma unroll 1
  for (int k0 = 0; k0 < HIDDEN; k0 += 32) {
    const int cur = (k0 >> 5) & 1;
    if (k0 + 32 < HIDDEN) stage(k0 + 32, cur ^ 1);
    const ushort_t* A = As + cur * 4096;
    const ushort_t* B = Bs + cur * 4096;
    bf16x8 a[4], b[4];
#pragma unroll
    for (int i = 0; i < 4; ++i)
      a[i] = *(const bf16x8*)(A + (wm + i * 16 + mq) * 32 + ((quad ^ sw) << 3));
#pragma unroll
    for (int j = 0; j < 4; ++j)
      b[j] = *(const bf16x8*)(B + (wn + j * 16 + mq) * 32 + ((quad ^ sw) << 3));
#pragma unroll
    for (int i = 0; i < 4; ++i)
#pragma unroll
      for (int j = 0; j < 4; ++j)
        acc[i][j] = mfma16(a[i], b[j], acc[i][j]);
    __syncthreads();
  }
}

// ================= fused QKV projection: 256x256 tile, 8-wave, 8-phase =================
// (R2/R5-measured core: ~129-132 us, MfmaUtil 32%, bank-conflict ~0. Proven pass.)
// RoPE is fused into the Q/K epilogue (pairs (d, d+64) are resident in-thread as
// acc[a][2cp] / acc[a][2cp+1]); rope_kernel is eliminated.

#define QKV_PHASE_MFMA(MH, NH, BB)                                                  \
  __builtin_amdgcn_s_barrier();                                                     \
  asm volatile("s_waitcnt lgkmcnt(0)" ::: "memory");                                \
  __builtin_amdgcn_s_setprio(1);                                                    \
  _Pragma("unroll") for (int f_ = 0; f_ < 4; ++f_)                                  \
  _Pragma("unroll") for (int n_ = 0; n_ < 2; ++n_)                                  \
  _Pragma("unroll") for (int kk_ = 0; kk_ < 2; ++kk_)                               \
    acc[(MH)*4+f_][(NH)*2+n_] =                                                     \
      mfma16(af[f_*2+kk_], BB[n_*2+kk_], acc[(MH)*4+f_][(NH)*2+n_]);                \
  __builtin_amdgcn_s_setprio(0);

#define QKV_TILE(CB, NB, KT)                                                        \
  {                                                                                 \
    const ushort_t* A_ = lds_q + (CB);                                              \
    const ushort_t* B_ = lds_q + (CB) + 16384;                                      \
    _Pragma("unroll") for (int u = 0; u < 8; ++u) af[u] = *(const bf16x8*)(A_ + aoff[u]); \
    _Pragma("unroll") for (int u = 0; u < 4; ++u) b0r[u] = *(const bf16x8*)(B_ + boff[u]); \
    stageA((KT), 0, (NB));                                                          \
    QKV_PHASE_MFMA(0, 0, b0r)                                                       \
    asm volatile("s_waitcnt vmcnt(4)" ::: "memory");                                \
    __builtin_amdgcn_s_barrier();                                                   \
    _Pragma("unroll") for (int u = 0; u < 4; ++u) b1r[u] = *(const bf16x8*)(B_ + 8192 + boff[u]); \
    stageB((KT), 0, (NB));                                                          \
    QKV_PHASE_MFMA(0, 1, b1r)                                                       \
    asm volatile("s_waitcnt vmcnt(4)" ::: "memory");                                \
    __builtin_amdgcn_s_barrier();                                                   \
    _Pragma("unroll") for (int u = 0; u < 8; ++u) af[u] = *(const bf16x8*)(A_ + 8192 + aoff[u]); \
    stageB((KT), 1, (NB));                                                          \
    QKV_PHASE_MFMA(1, 1, b1r)                                                       \
    __builtin_amdgcn_s_barrier();                                                   \
    stageA((KT), 1, (NB));                                                          \
    QKV_PHASE_MFMA(1, 0, b0r)                                                       \
    asm volatile("s_waitcnt vmcnt(4)" ::: "memory");                                \
    __builtin_amdgcn_s_barrier();                                                   \
  }

#define QKV_TAIL(CB)                                                                \
  {                                                                                 \
    const ushort_t* A_ = lds_q + (CB);                                              \
    const ushort_t* B_ = lds_q + (CB) + 16384;                                      \
    _Pragma("unroll") for (int u = 0; u < 8; ++u) af[u] = *(const bf16x8*)(A_ + aoff[u]); \
    _Pragma("unroll") for (int u = 0; u < 4; ++u) b0r[u] = *(const bf16x8*)(B_ + boff[u]); \
    QKV_PHASE_MFMA(0, 0, b0r)                                                       \
    asm volatile("s_waitcnt vmcnt(2)" ::: "memory");                                \
    __builtin_amdgcn_s_barrier();                                                   \
    _Pragma("unroll") for (int u = 0; u < 4; ++u) b1r[u] = *(const bf16x8*)(B_ + 8192 + boff[u]); \
    QKV_PHASE_MFMA(0, 1, b1r)                                                       \
    asm volatile("s_waitcnt vmcnt(0)" ::: "memory");                                \
    __builtin_amdgcn_s_barrier();                                                   \
    _Pragma("unroll") for (int u = 0; u < 8; ++u) af[u] = *(const bf16x8*)(A_ + 8192 + aoff[u]); \
    QKV_PHASE_MFMA(1, 1, b1r)                                                       \
    __builtin_amdgcn_s_barrier();                                                   \
    QKV_PHASE_MFMA(1, 0, b0r)                                                       \
  }

__global__ __launch_bounds__(512, 2) void qkv_gemm(const ushort_t* __restrict__ X,
                                                   const ushort_t* __restrict__ Wq,
                                                   const ushort_t* __restrict__ Wk,
                                                   const ushort_t* __restrict__ Wv,
                                                   ushort_t* __restrict__ Q,
                                                   ushort_t* __restrict__ K,
                                                   ushort_t* __restrict__ Vt) {
  __shared__ __align__(16) ushort_t lds_q[65536];   // 128 KiB

  const int tid = threadIdx.x, lane = tid & 63, wv = tid >> 6;
  const int wr = wv >> 2, wc = wv & 3;
  const int mq = lane & 15, quad = lane >> 4;
  const int lr = lane >> 3;
  const int csw = ((lane & 7) ^ (lr & 7)) * 8;      // pre-swizzled source col (elems)

  // block mapping: 384 blocks, XCD gets 3 consecutive N-panels (3 MB, L2-resident)
  const int lin = blockIdx.x;
  const int xcd = lin & 7, s = lin >> 3;            // s in [0,48)
  const int by = xcd * 3 + (s % 3);                 // 24 N-tiles
  const int bx = s / 3;                             // 16 M-tiles
  const int m0 = bx * 256;
  const int nglob = by * 256;
  const int which = nglob >> 11;
  const int n0 = nglob & 2047;
  const ushort_t* Ag = X + (size_t)m0 * HIDDEN;
  const ushort_t* Bg = ((which == 0) ? Wq : (which == 1) ? Wk : Wv) + (size_t)n0 * HIDDEN;

  // LDS read offsets (elems). Fragment interleave: wave wr owns M rows {f*32 + wr*16 + mq},
  // wave wc owns N cols {n*64 + wc*16 + mq} -> phase (mh,nh) touches exactly half (mh)/(nh).
  int aoff[8], boff[4];
#pragma unroll
  for (int f = 0; f < 4; ++f)
#pragma unroll
    for (int kk = 0; kk < 2; ++kk)
      aoff[f * 2 + kk] = (f * 32 + wr * 16 + mq) * 64 + (((kk * 4 + quad) ^ (mq & 7)) * 8);
#pragma unroll
  for (int n = 0; n < 2; ++n)
#pragma unroll
    for (int kk = 0; kk < 2; ++kk)
      boff[n * 2 + kk] = (n * 64 + wc * 16 + mq) * 64 + (((kk * 4 + quad) ^ (mq & 7)) * 8);

  auto stageA = [&](int kt, int half, int nb) {
#pragma unroll
    for (int i = 0; i < 2; ++i) {
      int seg = wv + i * 8;
      const ushort_t* src = Ag + (size_t)(half * 128 + seg * 8 + lr) * HIDDEN + kt * 64 + csw;
      __builtin_amdgcn_global_load_lds((AS1 void*)src,
                                       (AS3 void*)(lds_q + nb + half * 8192 + seg * 512), 16, 0, 0);
    }
  };
  auto stageB = [&](int kt, int half, int nb) {
#pragma unroll
    for (int i = 0; i < 2; ++i) {
      int seg = wv + i * 8;
      const ushort_t* src = Bg + (size_t)(half * 128 + seg * 8 + lr) * HIDDEN + kt * 64 + csw;
      __builtin_amdgcn_global_load_lds((AS1 void*)src,
                                       (AS3 void*)(lds_q + nb + 16384 + half * 8192 + seg * 512), 16, 0, 0);
    }
  };

  f32x4 acc[8][4];
  const f32x4 zf = {0.f, 0.f, 0.f, 0.f};
#pragma unroll
  for (int i = 0; i < 8; ++i)
#pragma unroll
    for (int j = 0; j < 4; ++j) acc[i][j] = zf;

  bf16x8 af[8], b0r[4], b1r[4];

  // prologue: tile 0, issue order == consumption order (A0,B0,B1,A1)
  stageA(0, 0, 0);
  stageB(0, 0, 0);
  stageB(0, 1, 0);
  stageA(0, 1, 0);
  __syncthreads();

#pragma unroll 1
  for (int tp = 0; tp < 15; ++tp) {
    QKV_TILE(0, 32768, 2 * tp + 1)
    QKV_TILE(32768, 0, 2 * tp + 2)
  }
  QKV_TILE(0, 32768, 31)
  QKV_TAIL(32768)

  // -------- epilogue --------
  // acc[a][c]: M row = m0 + (a>>2)*128 + (a&3)*32 + wr*16 + quad*4 + r
  //            N col = n0 + (c>>1)*128 + (c&1)*64 + wc*16 + mq
  // For Q/K: columns (c=2cp, c=2cp+1) are (d_low, d_low+64) of the SAME rows with
  // d_low = wc*16+mq < 64 -> apply RoPE in-register (fp32), single bf16 rounding.
  if (which != 2) {
    ushort_t* dst = (which == 0) ? Q : K;
    const float qscale = (which == 0) ? 0.08838834764831845f : 1.0f;
    const int dl = wc * 16 + mq;                         // d_low in [0,64)
    const float invf = exp2f((float)dl * -0.2076205059304601f);
#pragma unroll
    for (int a = 0; a < 8; ++a) {
#pragma unroll
      for (int r = 0; r < 4; ++r) {
        int mrow = m0 + (a >> 2) * 128 + (a & 3) * 32 + wr * 16 + quad * 4 + r;
        int bb = mrow >> 11, sq = mrow & (SEQ - 1);
        float sn, cs;
        sincosf((float)sq * invf, &sn, &cs);
#pragma unroll
        for (int cp = 0; cp < 2; ++cp) {
          float lo = acc[a][cp * 2][r], hi = acc[a][cp * 2 + 1][r];
          float nlo = (lo * cs - hi * sn) * qscale;
          float nhi = (hi * cs + lo * sn) * qscale;
          int ocol = n0 + cp * 128 + dl;                 // low-half column
          int hh = ocol >> 7;
          size_t base = ((size_t)(bb * NHEADS + hh) * SEQ + sq) * HDIM + dl;
          dst[base]      = f2bf(nlo);
          dst[base + 64] = f2bf(nhi);
        }
      }
    }
  } else {
    // V: transpose 256x256 through the full staging LDS -> coalesced uint4 stores to Vt
    __syncthreads();
#pragma unroll
    for (int a = 0; a < 8; ++a)
#pragma unroll
      for (int c4 = 0; c4 < 4; ++c4) {
        int cc = (c4 >> 1) * 128 + (c4 & 1) * 64 + wc * 16 + mq;
        int mb = (a >> 2) * 128 + (a & 3) * 32 + wr * 16 + quad * 4;
        uint32_t lo = (uint32_t)f2bf(acc[a][c4][0]) | ((uint32_t)f2bf(acc[a][c4][1]) << 16);
        uint32_t hi = (uint32_t)f2bf(acc[a][c4][2]) | ((uint32_t)f2bf(acc[a][c4][3]) << 16);
        *(uint2*)(lds_q + cc * 256 + (mb ^ ((cc & 7) * 8))) = make_uint2(lo, hi);
      }
    __syncthreads();
    const int bb = m0 >> 11, sq0 = m0 & (SEQ - 1);
#pragma unroll
    for (int it = 0; it < 16; ++it) {
      int cc = it * 16 + (tid >> 5);
      int sc = tid & 31;
      uint4 v = *(const uint4*)(lds_q + cc * 256 + ((sc ^ (cc & 7)) * 8));
      int hh = (n0 + cc) >> 7, d = (n0 + cc) & (HDIM - 1);
      *(uint4*)(Vt + ((size_t)(bb * NHEADS + hh) * HDIM + d) * SEQ + sq0 + sc * 8) = v;
    }
  }
}

// ---------------- causal flash attention: balanced pairs + transposed scores ----
// (R2-proven version: sequential pair (T, 15-T) -> uniform 34 steps/block, 256 blocks.)
__global__ __launch_bounds__(256, 1) void flash_kernel(const ushort_t* __restrict__ Q,
                                                       const ushort_t* __restrict__ K,
                                                       const ushort_t* __restrict__ Vt,
                                                       ushort_t* __restrict__ Ao) {
  __shared__ __align__(16) ushort_t sK[2][64 * 128];   // keys: 64 rows x 128 d
  __shared__ __align__(16) ushort_t sV[2][128 * 64];   // V^T: 128 d x 64 keys
  __shared__ __align__(16) ushort_t sP[128 * 64];      // P^T as [q][key], wave-private bands
  ushort_t* sO = &sK[0][0];                            // 128x128 epilogue scratch (32KB)

  const int tid = threadIdx.x, lane = tid & 63, wv = tid >> 6;
  const int lq = lane & 15, quad = lane >> 4;
  const int lin = blockIdx.x;
  const int xcd = lin & 7, slot = lin >> 3;
  const int bh = xcd * 4 + (slot & 3);
  const int pair = slot >> 2;                          // 0..7
  const ushort_t* Qb = Q + (size_t)bh * SEQ * HDIM;
  const ushort_t* Kb = K + (size_t)bh * SEQ * HDIM;
  const ushort_t* Vb = Vt + (size_t)bh * HDIM * SEQ;
  const int b = bh >> 4, h = bh & 15;

  auto stageK = [&](int j, ushort_t* dst) {
    int rr = lane >> 4, g = lane & 15;
#pragma unroll
    for (int t = 0; t < 4; ++t) {
      int chunk = wv * 4 + t;
      int row = chunk * 4 + rr;
      int gs = (g ^ (row & 7)) * 8;
      __builtin_amdgcn_global_load_lds((AS1 void*)(Kb + (size_t)(j * 64 + row) * HDIM + gs),
                                       (AS3 void*)(dst + chunk * 512), 16, 0, 0);
    }
  };
  auto stageV = [&](int j, ushort_t* dst) {
    int rr = lane >> 3, g = lane & 7;
#pragma unroll
    for (int t = 0; t < 4; ++t) {
      int chunk = wv * 4 + t;
      int row = chunk * 8 + rr;
      int gs = (g ^ (row & 7)) * 8;
      __builtin_amdgcn_global_load_lds((AS1 void*)(Vb + (size_t)row * SEQ + j * 64 + gs),
                                       (AS3 void*)(dst + chunk * 512), 16, 0, 0);
    }
  };

  const f32x4 zf = {0.f, 0.f, 0.f, 0.f};

#pragma unroll 1
  for (int phase = 0; phase < 2; ++phase) {
    const int T = phase ? (15 - pair) : pair;
    const int nsteps = 2 * T + 2;

    bf16x8 qf[2][4];
#pragma unroll
    for (int n = 0; n < 2; ++n)
#pragma unroll
      for (int kt = 0; kt < 4; ++kt)
        qf[n][kt] = *(const bf16x8*)(Qb + (size_t)(T * 128 + wv * 32 + n * 16 + lq) * HDIM +
                                     kt * 32 + quad * 8);

    float m_i[2] = {-1e30f, -1e30f}, l_i[2] = {0.f, 0.f};
    f32x4 oacc[8][2];
#pragma unroll
    for (int m = 0; m < 8; ++m)
#pragma unroll
      for (int n = 0; n < 2; ++n) oacc[m][n] = zf;

    __syncthreads();
    stageK(0, sK[0]);
    stageV(0, sV[0]);
    __syncthreads();

#pragma unroll 1
    for (int j = 0; j < nsteps; ++j) {
      const int cur = j & 1;
      if (j + 1 < nsteps) {
        stageK(j + 1, sK[cur ^ 1]);
        stageV(j + 1, sV[cur ^ 1]);
      }

      const ushort_t* sKc = sK[cur];
      f32x4 sacc[4][2];
#pragma unroll
      for (int m = 0; m < 4; ++m)
#pragma unroll
        for (int n = 0; n < 2; ++n) sacc[m][n] = zf;
#pragma unroll
      for (int kt = 0; kt < 4; ++kt) {
        bf16x8 kf[4];
#pragma unroll
        for (int m = 0; m < 4; ++m) {
          int row = m * 16 + lq;
          kf[m] = *(const bf16x8*)(sKc + row * 128 + (((kt * 4 + quad) ^ (row & 7)) * 8));
        }
#pragma unroll
        for (int m = 0; m < 4; ++m)
#pragma unroll
          for (int n = 0; n < 2; ++n)
            sacc[m][n] = mfma16(kf[m], qf[n][kt], sacc[m][n]);
      }

      const bool diag = (j >= 2 * T);
#pragma unroll
      for (int n = 0; n < 2; ++n) {
        const int qr = wv * 32 + n * 16 + lq;
        if (diag) {
          const int rowg = T * 128 + qr;
#pragma unroll
          for (int m = 0; m < 4; ++m)
#pragma unroll
            for (int r = 0; r < 4; ++r) {
              int key = j * 64 + m * 16 + quad * 4 + r;
              if (key > rowg) sacc[m][n][r] = -1e30f;
            }
        }
        float rm = -1e30f;
#pragma unroll
        for (int m = 0; m < 4; ++m)
#pragma unroll
          for (int r = 0; r < 4; ++r) rm = fmaxf(rm, sacc[m][n][r]);
        rm = fmaxf(rm, __shfl_xor(rm, 16, 64));
        rm = fmaxf(rm, __shfl_xor(rm, 32, 64));
        float mnew = fmaxf(m_i[n], rm);
        float alpha = __expf(m_i[n] - mnew);
        m_i[n] = mnew;
        float rs = 0.f;
#pragma unroll
        for (int m = 0; m < 4; ++m)
#pragma unroll
          for (int r = 0; r < 4; ++r) {
            float p = __expf(sacc[m][n][r] - mnew);
            sacc[m][n][r] = p;
            rs += p;
          }
        rs += __shfl_xor(rs, 16, 64);
        rs += __shfl_xor(rs, 32, 64);
        l_i[n] = l_i[n] * alpha + rs;
#pragma unroll
        for (int m = 0; m < 8; ++m)
#pragma unroll
          for (int r = 0; r < 4; ++r) oacc[m][n][r] *= alpha;
#pragma unroll
        for (int m = 0; m < 4; ++m) {
          uint32_t lo = (uint32_t)f2bf(sacc[m][n][0]) | ((uint32_t)f2bf(sacc[m][n][1]) << 16);
          uint32_t hi = (uint32_t)f2bf(sacc[m][n][2]) | ((uint32_t)f2bf(sacc[m][n][3]) << 16);
          int gw = m * 2 + (quad >> 1);
          *(uint2*)(sP + qr * 64 + ((gw ^ (qr & 7)) * 8) + (quad & 1) * 4) = make_uint2(lo, hi);
        }
      }

      const ushort_t* sVc = sV[cur];
#pragma unroll
      for (int kt = 0; kt < 2; ++kt) {
        bf16x8 pf[2];
#pragma unroll
        for (int n = 0; n < 2; ++n) {
          int qr = wv * 32 + n * 16 + lq;
          pf[n] = *(const bf16x8*)(sP + qr * 64 + (((kt * 4 + quad) ^ (qr & 7)) * 8));
        }
#pragma unroll
        for (int m = 0; m < 8; ++m) {
          int d = m * 16 + lq;
          bf16x8 vf = *(const bf16x8*)(sVc + d * 64 + (((kt * 4 + quad) ^ (d & 7)) * 8));
#pragma unroll
          for (int n = 0; n < 2; ++n)
            oacc[m][n] = mfma16(vf, pf[n], oacc[m][n]);
        }
      }

      __syncthreads();
    }

    float inv0 = 1.f / l_i[0], inv1 = 1.f / l_i[1];
#pragma unroll
    for (int n = 0; n < 2; ++n) {
      float inv = n ? inv1 : inv0;
      int qr = wv * 32 + n * 16 + lq;
#pragma unroll
      for (int m = 0; m < 8; ++m) {
        uint32_t lo = (uint32_t)f2bf(oacc[m][n][0] * inv) | ((uint32_t)f2bf(oacc[m][n][1] * inv) << 16);
        uint32_t hi = (uint32_t)f2bf(oacc[m][n][2] * inv) | ((uint32_t)f2bf(oacc[m][n][3] * inv) << 16);
        int gw = m * 2 + (quad >> 1);
        *(uint2*)(sO + qr * 128 + ((gw ^ (qr & 7)) * 8) + (quad & 1) * 4) = make_uint2(lo, hi);
      }
    }
    __syncthreads();
#pragma unroll
    for (int it = 0; it < 8; ++it) {
      int qr = it * 16 + (tid >> 4);
      int g = tid & 15;
      uint4 v = *(const uint4*)(sO + qr * 128 + ((g ^ (qr & 7)) * 8));
      *(uint4*)(Ao + ((size_t)(b * SEQ + T * 128 + qr)) * (NHEADS * HDIM) + h * HDIM + g * 8) = v;
    }
  }
}

// ---------------- output projection (fp32 out, XCD-swizzled) ----------------
__global__ __launch_bounds__(256) void out_gemm(const ushort_t* __restrict__ Ain,
                                                const ushort_t* __restrict__ Wo,
                                                float* __restrict__ Y) {
  __shared__ __align__(16) ushort_t As[2][128 * 32];
  __shared__ __align__(16) ushort_t Bs[2][128 * 32];
  const int tid = threadIdx.x;
  const int lin = blockIdx.x;
  const int xcd = lin & 7, s = lin >> 3;
  const int by = xcd + 8 * (s & 1);
  const int bx = s >> 1;
  const int m0 = bx * 128;
  const int n0 = by * 128;

  f32x4 acc[4][4];
  const f32x4 zf = {0.f, 0.f, 0.f, 0.f};
#pragma unroll
  for (int i = 0; i < 4; ++i)
#pragma unroll
    for (int j = 0; j < 4; ++j) acc[i][j] = zf;

  gemm128_core(Ain + (size_t)m0 * HIDDEN, Wo + (size_t)n0 * HIDDEN, &As[0][0], &Bs[0][0], acc, tid);

  const int lane = tid & 63, wv = tid >> 6;
  const int wm = (wv >> 1) * 64, wn = (wv & 1) * 64;
  const int mq = lane & 15, quad = lane >> 4;
#pragma unroll
  for (int i = 0; i < 4; ++i)
#pragma unroll
    for (int j = 0; j < 4; ++j)
#pragma unroll
      for (int r = 0; r < 4; ++r) {
        int m = m0 + wm + i * 16 + quad * 4 + r;
        int o = n0 + wn + j * 16 + mq;
        Y[(size_t)m * HIDDEN + o] = acc[i][j][r];
      }
}

extern "C" void kernel_launch(void* const* d_in, const int* in_sizes, int n_in,
                              void* d_out, int out_size, void* d_ws, size_t ws_size,
                              hipStream_t stream) {
  const float* hs = (const float*)d_in[0];
  const float* Wq = (const float*)d_in[1];
  const float* Wk = (const float*)d_in[2];
  const float* Wv = (const float*)d_in[3];
  const float* Wo = (const float*)d_in[4];
  float* out = (float*)d_out;

  ushort_t* ws  = (ushort_t*)d_ws;
  ushort_t* Xb  = ws;
  ushort_t* Wqb = Xb  + (size_t)MROWS * HIDDEN;
  ushort_t* Wkb = Wqb + (size_t)HIDDEN * HIDDEN;
  ushort_t* Wvb = Wkb + (size_t)HIDDEN * HIDDEN;
  ushort_t* Wob = Wvb + (size_t)HIDDEN * HIDDEN;
  ushort_t* Qb  = Wob + (size_t)HIDDEN * HIDDEN;
  ushort_t* Kb  = Qb  + (size_t)MROWS * HIDDEN;
  ushort_t* Vtb = Kb  + (size_t)MROWS * HIDDEN;
  ushort_t* Ao  = Vtb + (size_t)MROWS * HIDDEN;

  cvt_kernel<<<(MROWS * HIDDEN / 4) / 256, 256, 0, stream>>>(hs, Xb, MROWS * HIDDEN / 4);
  cvt4_kernel<<<dim3((HIDDEN * HIDDEN / 4) / 256, 4), 256, 0, stream>>>(
      Wq, Wk, Wv, Wo, Wqb, Wkb, Wvb, Wob);

  qkv_gemm<<<dim3(384), 512, 0, stream>>>(Xb, Wqb, Wkb, Wvb, Qb, Kb, Vtb);
  flash_kernel<<<dim3(256), 256, 0, stream>>>(Qb, Kb, Vtb, Ao);
  out_gemm<<<dim3(512), 256, 0, stream>>>(Ao, Wob, out);
}

// Round 8
// 395.809 us; speedup vs baseline: 1.1115x; 1.0466x over previous
//
#include <hip/hip_runtime.h>
#include <stdint.h>

typedef unsigned short ushort_t;
typedef __attribute__((ext_vector_type(8))) __bf16 bf16x8;
typedef __attribute__((ext_vector_type(4))) float f32x4;

#define HIDDEN 2048
#define NHEADS 16
#define HDIM 128
#define SEQ 2048
#define BATCH 2
#define MROWS (BATCH*SEQ)

#define AS1 __attribute__((address_space(1)))
#define AS3 __attribute__((address_space(3)))

__device__ __forceinline__ ushort_t f2bf(float f) {
  uint32_t u = __float_as_uint(f);
  u += 0x7FFFu + ((u >> 16) & 1u);
  return (ushort_t)(u >> 16);
}
__device__ __forceinline__ float bf2f(ushort_t h) {
  return __uint_as_float((uint32_t)h << 16);
}

__device__ __forceinline__ f32x4 mfma16(bf16x8 a, bf16x8 b, f32x4 c) {
  return __builtin_amdgcn_mfma_f32_16x16x32_bf16(a, b, c, 0, 0, 0);
}

// ---------------- fp32 -> bf16 converts (+ RoPE table fill) ----------------
// RoTab[s*64+dl] = (cos, sin)(s * 10000^(-dl/64)) -- same formula as the R6-passing
// epilogue sincosf, so downstream math is bit-identical to the R6 pass.
__global__ void cvt_kernel(const float* __restrict__ in, ushort_t* __restrict__ out,
                           float2* __restrict__ rotab, int n4) {
  int i = blockIdx.x * blockDim.x + threadIdx.x;
  if (i < n4) {
    float4 v = ((const float4*)in)[i];
    uint32_t lo = (uint32_t)f2bf(v.x) | ((uint32_t)f2bf(v.y) << 16);
    uint32_t hi = (uint32_t)f2bf(v.z) | ((uint32_t)f2bf(v.w) << 16);
    ((uint2*)out)[i] = make_uint2(lo, hi);
  }
  if (i < SEQ * 64) {
    int s = i >> 6, dl = i & 63;
    float th = exp2f((float)dl * -0.2076205059304601f);
    float sn, cs;
    sincosf((float)s * th, &sn, &cs);
    rotab[i] = make_float2(cs, sn);
  }
}

__global__ void cvt4_kernel(const float* __restrict__ w0, const float* __restrict__ w1,
                            const float* __restrict__ w2, const float* __restrict__ w3,
                            ushort_t* __restrict__ o0, ushort_t* __restrict__ o1,
                            ushort_t* __restrict__ o2, ushort_t* __restrict__ o3) {
  int y = blockIdx.y;
  const float* in = (y == 0) ? w0 : (y == 1) ? w1 : (y == 2) ? w2 : w3;
  ushort_t* out = (y == 0) ? o0 : (y == 1) ? o1 : (y == 2) ? o2 : o3;
  int i = blockIdx.x * blockDim.x + threadIdx.x;
  float4 v = ((const float4*)in)[i];
  uint32_t lo = (uint32_t)f2bf(v.x) | ((uint32_t)f2bf(v.y) << 16);
  uint32_t hi = (uint32_t)f2bf(v.z) | ((uint32_t)f2bf(v.w) << 16);
  ((uint2*)out)[i] = make_uint2(lo, hi);
}

// ------- 128x128x2048 GEMM core (kept for out_gemm) -------
__device__ __forceinline__ void gemm128_core(const ushort_t* __restrict__ Ag,
                                             const ushort_t* __restrict__ Bg,
                                             ushort_t* As, ushort_t* Bs,  // each 2*4096
                                             f32x4 acc[4][4], int tid) {
  const int lane = tid & 63, wv = tid >> 6;
  const int r4 = lane >> 2;
  const int c8 = (((lane & 3) ^ ((r4 >> 1) & 3)) << 3);
  const int wm = (wv >> 1) * 64, wn = (wv & 1) * 64;
  const int mq = lane & 15, quad = lane >> 4;
  const int sw = (mq >> 1) & 3;

  auto stage = [&](int k0, int buf) {
#pragma unroll
    for (int cc = 0; cc < 2; ++cc) {
      int chunk = wv + cc * 4;
      const ushort_t* ga = Ag + (size_t)(chunk * 16 + r4) * HIDDEN + k0 + c8;
      const ushort_t* gb = Bg + (size_t)(chunk * 16 + r4) * HIDDEN + k0 + c8;
      __builtin_amdgcn_global_load_lds((AS1 void*)ga, (AS3 void*)(As + buf * 4096 + chunk * 512), 16, 0, 0);
      __builtin_amdgcn_global_load_lds((AS1 void*)gb, (AS3 void*)(Bs + buf * 4096 + chunk * 512), 16, 0, 0);
    }
  };

  stage(0, 0);
  __syncthreads();
#pragma unroll 1
  for (int k0 = 0; k0 < HIDDEN; k0 += 32) {
    const int cur = (k0 >> 5) & 1;
    if (k0 + 32 < HIDDEN) stage(k0 + 32, cur ^ 1);
    const ushort_t* A = As + cur * 4096;
    const ushort_t* B = Bs + cur * 4096;
    bf16x8 a[4], b[4];
#pragma unroll
    for (int i = 0; i < 4; ++i)
      a[i] = *(const bf16x8*)(A + (wm + i * 16 + mq) * 32 + ((quad ^ sw) << 3));
#pragma unroll
    for (int j = 0; j < 4; ++j)
      b[j] = *(const bf16x8*)(B + (wn + j * 16 + mq) * 32 + ((quad ^ sw) << 3));
#pragma unroll
    for (int i = 0; i < 4; ++i)
#pragma unroll
      for (int j = 0; j < 4; ++j)
        acc[i][j] = mfma16(a[i], b[j], acc[i][j]);
    __syncthreads();
  }
}

// ================= fused QKV projection: 256x256 tile, 8-wave, 8-phase =================
// (R2/R5-measured core: ~129-132 us, MfmaUtil 32%, bank-conflict ~0. Proven pass.)
// RoPE fused into the Q/K epilogue via the precomputed RoTab (one 8B L2 load per (a,r)).
// R6 lesson: 32 sincosf/thread cost +11.5us. R7 lesson: incremental-rotation chain
// failed correctness (unexplained) -- table is bit-identical to the R6-passing math.

#define QKV_PHASE_MFMA(MH, NH, BB)                                                  \
  __builtin_amdgcn_s_barrier();                                                     \
  asm volatile("s_waitcnt lgkmcnt(0)" ::: "memory");                                \
  __builtin_amdgcn_s_setprio(1);                                                    \
  _Pragma("unroll") for (int f_ = 0; f_ < 4; ++f_)                                  \
  _Pragma("unroll") for (int n_ = 0; n_ < 2; ++n_)                                  \
  _Pragma("unroll") for (int kk_ = 0; kk_ < 2; ++kk_)                               \
    acc[(MH)*4+f_][(NH)*2+n_] =                                                     \
      mfma16(af[f_*2+kk_], BB[n_*2+kk_], acc[(MH)*4+f_][(NH)*2+n_]);                \
  __builtin_amdgcn_s_setprio(0);

#define QKV_TILE(CB, NB, KT)                                                        \
  {                                                                                 \
    const ushort_t* A_ = lds_q + (CB);                                              \
    const ushort_t* B_ = lds_q + (CB) + 16384;                                      \
    _Pragma("unroll") for (int u = 0; u < 8; ++u) af[u] = *(const bf16x8*)(A_ + aoff[u]); \
    _Pragma("unroll") for (int u = 0; u < 4; ++u) b0r[u] = *(const bf16x8*)(B_ + boff[u]); \
    stageA((KT), 0, (NB));                                                          \
    QKV_PHASE_MFMA(0, 0, b0r)                                                       \
    asm volatile("s_waitcnt vmcnt(4)" ::: "memory");                                \
    __builtin_amdgcn_s_barrier();                                                   \
    _Pragma("unroll") for (int u = 0; u < 4; ++u) b1r[u] = *(const bf16x8*)(B_ + 8192 + boff[u]); \
    stageB((KT), 0, (NB));                                                          \
    QKV_PHASE_MFMA(0, 1, b1r)                                                       \
    asm volatile("s_waitcnt vmcnt(4)" ::: "memory");                                \
    __builtin_amdgcn_s_barrier();                                                   \
    _Pragma("unroll") for (int u = 0; u < 8; ++u) af[u] = *(const bf16x8*)(A_ + 8192 + aoff[u]); \
    stageB((KT), 1, (NB));                                                          \
    QKV_PHASE_MFMA(1, 1, b1r)                                                       \
    __builtin_amdgcn_s_barrier();                                                   \
    stageA((KT), 1, (NB));                                                          \
    QKV_PHASE_MFMA(1, 0, b0r)                                                       \
    asm volatile("s_waitcnt vmcnt(4)" ::: "memory");                                \
    __builtin_amdgcn_s_barrier();                                                   \
  }

#define QKV_TAIL(CB)                                                                \
  {                                                                                 \
    const ushort_t* A_ = lds_q + (CB);                                              \
    const ushort_t* B_ = lds_q + (CB) + 16384;                                      \
    _Pragma("unroll") for (int u = 0; u < 8; ++u) af[u] = *(const bf16x8*)(A_ + aoff[u]); \
    _Pragma("unroll") for (int u = 0; u < 4; ++u) b0r[u] = *(const bf16x8*)(B_ + boff[u]); \
    QKV_PHASE_MFMA(0, 0, b0r)                                                       \
    asm volatile("s_waitcnt vmcnt(2)" ::: "memory");                                \
    __builtin_amdgcn_s_barrier();                                                   \
    _Pragma("unroll") for (int u = 0; u < 4; ++u) b1r[u] = *(const bf16x8*)(B_ + 8192 + boff[u]); \
    QKV_PHASE_MFMA(0, 1, b1r)                                                       \
    asm volatile("s_waitcnt vmcnt(0)" ::: "memory");                                \
    __builtin_amdgcn_s_barrier();                                                   \
    _Pragma("unroll") for (int u = 0; u < 8; ++u) af[u] = *(const bf16x8*)(A_ + 8192 + aoff[u]); \
    QKV_PHASE_MFMA(1, 1, b1r)                                                       \
    __builtin_amdgcn_s_barrier();                                                   \
    QKV_PHASE_MFMA(1, 0, b0r)                                                       \
  }

__global__ __launch_bounds__(512, 2) void qkv_gemm(const ushort_t* __restrict__ X,
                                                   const ushort_t* __restrict__ Wq,
                                                   const ushort_t* __restrict__ Wk,
                                                   const ushort_t* __restrict__ Wv,
                                                   const float2* __restrict__ RoTab,
                                                   ushort_t* __restrict__ Q,
                                                   ushort_t* __restrict__ K,
                                                   ushort_t* __restrict__ Vt) {
  __shared__ __align__(16) ushort_t lds_q[65536];   // 128 KiB

  const int tid = threadIdx.x, lane = tid & 63, wv = tid >> 6;
  const int wr = wv >> 2, wc = wv & 3;
  const int mq = lane & 15, quad = lane >> 4;
  const int lr = lane >> 3;
  const int csw = ((lane & 7) ^ (lr & 7)) * 8;      // pre-swizzled source col (elems)

  // block mapping: 384 blocks, XCD gets 3 consecutive N-panels (3 MB, L2-resident)
  const int lin = blockIdx.x;
  const int xcd = lin & 7, s = lin >> 3;            // s in [0,48)
  const int by = xcd * 3 + (s % 3);                 // 24 N-tiles
  const int bx = s / 3;                             // 16 M-tiles
  const int m0 = bx * 256;
  const int nglob = by * 256;
  const int which = nglob >> 11;
  const int n0 = nglob & 2047;
  const ushort_t* Ag = X + (size_t)m0 * HIDDEN;
  const ushort_t* Bg = ((which == 0) ? Wq : (which == 1) ? Wk : Wv) + (size_t)n0 * HIDDEN;

  // LDS read offsets (elems). Fragment interleave: wave wr owns M rows {f*32 + wr*16 + mq},
  // wave wc owns N cols {n*64 + wc*16 + mq} -> phase (mh,nh) touches exactly half (mh)/(nh).
  int aoff[8], boff[4];
#pragma unroll
  for (int f = 0; f < 4; ++f)
#pragma unroll
    for (int kk = 0; kk < 2; ++kk)
      aoff[f * 2 + kk] = (f * 32 + wr * 16 + mq) * 64 + (((kk * 4 + quad) ^ (mq & 7)) * 8);
#pragma unroll
  for (int n = 0; n < 2; ++n)
#pragma unroll
    for (int kk = 0; kk < 2; ++kk)
      boff[n * 2 + kk] = (n * 64 + wc * 16 + mq) * 64 + (((kk * 4 + quad) ^ (mq & 7)) * 8);

  auto stageA = [&](int kt, int half, int nb) {
#pragma unroll
    for (int i = 0; i < 2; ++i) {
      int seg = wv + i * 8;
      const ushort_t* src = Ag + (size_t)(half * 128 + seg * 8 + lr) * HIDDEN + kt * 64 + csw;
      __builtin_amdgcn_global_load_lds((AS1 void*)src,
                                       (AS3 void*)(lds_q + nb + half * 8192 + seg * 512), 16, 0, 0);
    }
  };
  auto stageB = [&](int kt, int half, int nb) {
#pragma unroll
    for (int i = 0; i < 2; ++i) {
      int seg = wv + i * 8;
      const ushort_t* src = Bg + (size_t)(half * 128 + seg * 8 + lr) * HIDDEN + kt * 64 + csw;
      __builtin_amdgcn_global_load_lds((AS1 void*)src,
                                       (AS3 void*)(lds_q + nb + 16384 + half * 8192 + seg * 512), 16, 0, 0);
    }
  };

  f32x4 acc[8][4];
  const f32x4 zf = {0.f, 0.f, 0.f, 0.f};
#pragma unroll
  for (int i = 0; i < 8; ++i)
#pragma unroll
    for (int j = 0; j < 4; ++j) acc[i][j] = zf;

  bf16x8 af[8], b0r[4], b1r[4];

  // prologue: tile 0, issue order == consumption order (A0,B0,B1,A1)
  stageA(0, 0, 0);
  stageB(0, 0, 0);
  stageB(0, 1, 0);
  stageA(0, 1, 0);
  __syncthreads();

#pragma unroll 1
  for (int tp = 0; tp < 15; ++tp) {
    QKV_TILE(0, 32768, 2 * tp + 1)
    QKV_TILE(32768, 0, 2 * tp + 2)
  }
  QKV_TILE(0, 32768, 31)
  QKV_TAIL(32768)

  // -------- epilogue --------
  // acc[a][c]: M row = m0 + (a>>2)*128 + (a&3)*32 + wr*16 + quad*4 + r
  //            N col = n0 + (c>>1)*128 + (c&1)*64 + wc*16 + mq
  // Q/K: columns (c=2cp, c=2cp+1) are (d_low, d_low+64) of the SAME rows with
  // d_low = wc*16+mq < 64 -> RoPE in-register (fp32) via RoTab, single bf16 rounding.
  if (which != 2) {
    ushort_t* dst = (which == 0) ? Q : K;
    const float qscale = (which == 0) ? 0.08838834764831845f : 1.0f;
    const int dl = wc * 16 + mq;                         // d_low in [0,64)
#pragma unroll
    for (int a = 0; a < 8; ++a) {
#pragma unroll
      for (int r = 0; r < 4; ++r) {
        int mrow = m0 + (a >> 2) * 128 + (a & 3) * 32 + wr * 16 + quad * 4 + r;
        int bb = mrow >> 11, sq = mrow & (SEQ - 1);
        float2 t = RoTab[(sq << 6) + dl];
        float cs = t.x, sn = t.y;
#pragma unroll
        for (int cp = 0; cp < 2; ++cp) {
          float lo = acc[a][cp * 2][r], hi = acc[a][cp * 2 + 1][r];
          float nlo = (lo * cs - hi * sn) * qscale;
          float nhi = (hi * cs + lo * sn) * qscale;
          int ocol = n0 + cp * 128 + dl;                 // low-half column
          int hh = ocol >> 7;
          size_t base = ((size_t)(bb * NHEADS + hh) * SEQ + sq) * HDIM + dl;
          dst[base]      = f2bf(nlo);
          dst[base + 64] = f2bf(nhi);
        }
      }
    }
  } else {
    // V: transpose 256x256 through the full staging LDS -> coalesced uint4 stores to Vt
    __syncthreads();
#pragma unroll
    for (int a = 0; a < 8; ++a)
#pragma unroll
      for (int c4 = 0; c4 < 4; ++c4) {
        int cc = (c4 >> 1) * 128 + (c4 & 1) * 64 + wc * 16 + mq;
        int mb = (a >> 2) * 128 + (a & 3) * 32 + wr * 16 + quad * 4;
        uint32_t lo = (uint32_t)f2bf(acc[a][c4][0]) | ((uint32_t)f2bf(acc[a][c4][1]) << 16);
        uint32_t hi = (uint32_t)f2bf(acc[a][c4][2]) | ((uint32_t)f2bf(acc[a][c4][3]) << 16);
        *(uint2*)(lds_q + cc * 256 + (mb ^ ((cc & 7) * 8))) = make_uint2(lo, hi);
      }
    __syncthreads();
    const int bb = m0 >> 11, sq0 = m0 & (SEQ - 1);
#pragma unroll
    for (int it = 0; it < 16; ++it) {
      int cc = it * 16 + (tid >> 5);
      int sc = tid & 31;
      uint4 v = *(const uint4*)(lds_q + cc * 256 + ((sc ^ (cc & 7)) * 8));
      int hh = (n0 + cc) >> 7, d = (n0 + cc) & (HDIM - 1);
      *(uint4*)(Vt + ((size_t)(bb * NHEADS + hh) * HDIM + d) * SEQ + sq0 + sc * 8) = v;
    }
  }
}

// ---------------- causal flash attention: balanced pairs + transposed scores ----
// (R2-proven version: sequential pair (T, 15-T) -> uniform 34 steps/block, 256 blocks.)
__global__ __launch_bounds__(256, 1) void flash_kernel(const ushort_t* __restrict__ Q,
                                                       const ushort_t* __restrict__ K,
                                                       const ushort_t* __restrict__ Vt,
                                                       ushort_t* __restrict__ Ao) {
  __shared__ __align__(16) ushort_t sK[2][64 * 128];   // keys: 64 rows x 128 d
  __shared__ __align__(16) ushort_t sV[2][128 * 64];   // V^T: 128 d x 64 keys
  __shared__ __align__(16) ushort_t sP[128 * 64];      // P^T as [q][key], wave-private bands
  ushort_t* sO = &sK[0][0];                            // 128x128 epilogue scratch (32KB)

  const int tid = threadIdx.x, lane = tid & 63, wv = tid >> 6;
  const int lq = lane & 15, quad = lane >> 4;
  const int lin = blockIdx.x;
  const int xcd = lin & 7, slot = lin >> 3;
  const int bh = xcd * 4 + (slot & 3);
  const int pair = slot >> 2;                          // 0..7
  const ushort_t* Qb = Q + (size_t)bh * SEQ * HDIM;
  const ushort_t* Kb = K + (size_t)bh * SEQ * HDIM;
  const ushort_t* Vb = Vt + (size_t)bh * HDIM * SEQ;
  const int b = bh >> 4, h = bh & 15;

  auto stageK = [&](int j, ushort_t* dst) {
    int rr = lane >> 4, g = lane & 15;
#pragma unroll
    for (int t = 0; t < 4; ++t) {
      int chunk = wv * 4 + t;
      int row = chunk * 4 + rr;
      int gs = (g ^ (row & 7)) * 8;
      __builtin_amdgcn_global_load_lds((AS1 void*)(Kb + (size_t)(j * 64 + row) * HDIM + gs),
                                       (AS3 void*)(dst + chunk * 512), 16, 0, 0);
    }
  };
  auto stageV = [&](int j, ushort_t* dst) {
    int rr = lane >> 3, g = lane & 7;
#pragma unroll
    for (int t = 0; t < 4; ++t) {
      int chunk = wv * 4 + t;
      int row = chunk * 8 + rr;
      int gs = (g ^ (row & 7)) * 8;
      __builtin_amdgcn_global_load_lds((AS1 void*)(Vb + (size_t)row * SEQ + j * 64 + gs),
                                       (AS3 void*)(dst + chunk * 512), 16, 0, 0);
    }
  };

  const f32x4 zf = {0.f, 0.f, 0.f, 0.f};

#pragma unroll 1
  for (int phase = 0; phase < 2; ++phase) {
    const int T = phase ? (15 - pair) : pair;
    const int nsteps = 2 * T + 2;

    bf16x8 qf[2][4];
#pragma unroll
    for (int n = 0; n < 2; ++n)
#pragma unroll
      for (int kt = 0; kt < 4; ++kt)
        qf[n][kt] = *(const bf16x8*)(Qb + (size_t)(T * 128 + wv * 32 + n * 16 + lq) * HDIM +
                                     kt * 32 + quad * 8);

    float m_i[2] = {-1e30f, -1e30f}, l_i[2] = {0.f, 0.f};
    f32x4 oacc[8][2];
#pragma unroll
    for (int m = 0; m < 8; ++m)
#pragma unroll
      for (int n = 0; n < 2; ++n) oacc[m][n] = zf;

    __syncthreads();
    stageK(0, sK[0]);
    stageV(0, sV[0]);
    __syncthreads();

#pragma unroll 1
    for (int j = 0; j < nsteps; ++j) {
      const int cur = j & 1;
      if (j + 1 < nsteps) {
        stageK(j + 1, sK[cur ^ 1]);
        stageV(j + 1, sV[cur ^ 1]);
      }

      const ushort_t* sKc = sK[cur];
      f32x4 sacc[4][2];
#pragma unroll
      for (int m = 0; m < 4; ++m)
#pragma unroll
        for (int n = 0; n < 2; ++n) sacc[m][n] = zf;
#pragma unroll
      for (int kt = 0; kt < 4; ++kt) {
        bf16x8 kf[4];
#pragma unroll
        for (int m = 0; m < 4; ++m) {
          int row = m * 16 + lq;
          kf[m] = *(const bf16x8*)(sKc + row * 128 + (((kt * 4 + quad) ^ (row & 7)) * 8));
        }
#pragma unroll
        for (int m = 0; m < 4; ++m)
#pragma unroll
          for (int n = 0; n < 2; ++n)
            sacc[m][n] = mfma16(kf[m], qf[n][kt], sacc[m][n]);
      }

      const bool diag = (j >= 2 * T);
#pragma unroll
      for (int n = 0; n < 2; ++n) {
        const int qr = wv * 32 + n * 16 + lq;
        if (diag) {
          const int rowg = T * 128 + qr;
#pragma unroll
          for (int m = 0; m < 4; ++m)
#pragma unroll
            for (int r = 0; r < 4; ++r) {
              int key = j * 64 + m * 16 + quad * 4 + r;
              if (key > rowg) sacc[m][n][r] = -1e30f;
            }
        }
        float rm = -1e30f;
#pragma unroll
        for (int m = 0; m < 4; ++m)
#pragma unroll
          for (int r = 0; r < 4; ++r) rm = fmaxf(rm, sacc[m][n][r]);
        rm = fmaxf(rm, __shfl_xor(rm, 16, 64));
        rm = fmaxf(rm, __shfl_xor(rm, 32, 64));
        float mnew = fmaxf(m_i[n], rm);
        float alpha = __expf(m_i[n] - mnew);
        m_i[n] = mnew;
        float rs = 0.f;
#pragma unroll
        for (int m = 0; m < 4; ++m)
#pragma unroll
          for (int r = 0; r < 4; ++r) {
            float p = __expf(sacc[m][n][r] - mnew);
            sacc[m][n][r] = p;
            rs += p;
          }
        rs += __shfl_xor(rs, 16, 64);
        rs += __shfl_xor(rs, 32, 64);
        l_i[n] = l_i[n] * alpha + rs;
#pragma unroll
        for (int m = 0; m < 8; ++m)
#pragma unroll
          for (int r = 0; r < 4; ++r) oacc[m][n][r] *= alpha;
#pragma unroll
        for (int m = 0; m < 4; ++m) {
          uint32_t lo = (uint32_t)f2bf(sacc[m][n][0]) | ((uint32_t)f2bf(sacc[m][n][1]) << 16);
          uint32_t hi = (uint32_t)f2bf(sacc[m][n][2]) | ((uint32_t)f2bf(sacc[m][n][3]) << 16);
          int gw = m * 2 + (quad >> 1);
          *(uint2*)(sP + qr * 64 + ((gw ^ (qr & 7)) * 8) + (quad & 1) * 4) = make_uint2(lo, hi);
        }
      }

      const ushort_t* sVc = sV[cur];
#pragma unroll
      for (int kt = 0; kt < 2; ++kt) {
        bf16x8 pf[2];
#pragma unroll
        for (int n = 0; n < 2; ++n) {
          int qr = wv * 32 + n * 16 + lq;
          pf[n] = *(const bf16x8*)(sP + qr * 64 + (((kt * 4 + quad) ^ (qr & 7)) * 8));
        }
#pragma unroll
        for (int m = 0; m < 8; ++m) {
          int d = m * 16 + lq;
          bf16x8 vf = *(const bf16x8*)(sVc + d * 64 + (((kt * 4 + quad) ^ (d & 7)) * 8));
#pragma unroll
          for (int n = 0; n < 2; ++n)
            oacc[m][n] = mfma16(vf, pf[n], oacc[m][n]);
        }
      }

      __syncthreads();
    }

    float inv0 = 1.f / l_i[0], inv1 = 1.f / l_i[1];
#pragma unroll
    for (int n = 0; n < 2; ++n) {
      float inv = n ? inv1 : inv0;
      int qr = wv * 32 + n * 16 + lq;
#pragma unroll
      for (int m = 0; m < 8; ++m) {
        uint32_t lo = (uint32_t)f2bf(oacc[m][n][0] * inv) | ((uint32_t)f2bf(oacc[m][n][1] * inv) << 16);
        uint32_t hi = (uint32_t)f2bf(oacc[m][n][2] * inv) | ((uint32_t)f2bf(oacc[m][n][3] * inv) << 16);
        int gw = m * 2 + (quad >> 1);
        *(uint2*)(sO + qr * 128 + ((gw ^ (qr & 7)) * 8) + (quad & 1) * 4) = make_uint2(lo, hi);
      }
    }
    __syncthreads();
#pragma unroll
    for (int it = 0; it < 8; ++it) {
      int qr = it * 16 + (tid >> 4);
      int g = tid & 15;
      uint4 v = *(const uint4*)(sO + qr * 128 + ((g ^ (qr & 7)) * 8));
      *(uint4*)(Ao + ((size_t)(b * SEQ + T * 128 + qr)) * (NHEADS * HDIM) + h * HDIM + g * 8) = v;
    }
  }
}

// ---------------- output projection (fp32 out, XCD-swizzled) ----------------
__global__ __launch_bounds__(256) void out_gemm(const ushort_t* __restrict__ Ain,
                                                const ushort_t* __restrict__ Wo,
                                                float* __restrict__ Y) {
  __shared__ __align__(16) ushort_t As[2][128 * 32];
  __shared__ __align__(16) ushort_t Bs[2][128 * 32];
  const int tid = threadIdx.x;
  const int lin = blockIdx.x;
  const int xcd = lin & 7, s = lin >> 3;
  const int by = xcd + 8 * (s & 1);
  const int bx = s >> 1;
  const int m0 = bx * 128;
  const int n0 = by * 128;

  f32x4 acc[4][4];
  const f32x4 zf = {0.f, 0.f, 0.f, 0.f};
#pragma unroll
  for (int i = 0; i < 4; ++i)
#pragma unroll
    for (int j = 0; j < 4; ++j) acc[i][j] = zf;

  gemm128_core(Ain + (size_t)m0 * HIDDEN, Wo + (size_t)n0 * HIDDEN, &As[0][0], &Bs[0][0], acc, tid);

  const int lane = tid & 63, wv = tid >> 6;
  const int wm = (wv >> 1) * 64, wn = (wv & 1) * 64;
  const int mq = lane & 15, quad = lane >> 4;
#pragma unroll
  for (int i = 0; i < 4; ++i)
#pragma unroll
    for (int j = 0; j < 4; ++j)
#pragma unroll
      for (int r = 0; r < 4; ++r) {
        int m = m0 + wm + i * 16 + quad * 4 + r;
        int o = n0 + wn + j * 16 + mq;
        Y[(size_t)m * HIDDEN + o] = acc[i][j][r];
      }
}

extern "C" void kernel_launch(void* const* d_in, const int* in_sizes, int n_in,
                              void* d_out, int out_size, void* d_ws, size_t ws_size,
                              hipStream_t stream) {
  const float* hs = (const float*)d_in[0];
  const float* Wq = (const float*)d_in[1];
  const float* Wk = (const float*)d_in[2];
  const float* Wv = (const float*)d_in[3];
  const float* Wo = (const float*)d_in[4];
  float* out = (float*)d_out;

  ushort_t* ws  = (ushort_t*)d_ws;
  ushort_t* Xb  = ws;
  ushort_t* Wqb = Xb  + (size_t)MROWS * HIDDEN;
  ushort_t* Wkb = Wqb + (size_t)HIDDEN * HIDDEN;
  ushort_t* Wvb = Wkb + (size_t)HIDDEN * HIDDEN;
  ushort_t* Wob = Wvb + (size_t)HIDDEN * HIDDEN;
  ushort_t* Qb  = Wob + (size_t)HIDDEN * HIDDEN;
  ushort_t* Kb  = Qb  + (size_t)MROWS * HIDDEN;
  ushort_t* Vtb = Kb  + (size_t)MROWS * HIDDEN;
  ushort_t* Ao  = Vtb + (size_t)MROWS * HIDDEN;
  float2*   RoTab = (float2*)(Ao + (size_t)MROWS * HIDDEN);

  cvt_kernel<<<(MROWS * HIDDEN / 4) / 256, 256, 0, stream>>>(hs, Xb, RoTab, MROWS * HIDDEN / 4);
  cvt4_kernel<<<dim3((HIDDEN * HIDDEN / 4) / 256, 4), 256, 0, stream>>>(
      Wq, Wk, Wv, Wo, Wqb, Wkb, Wvb, Wob);

  qkv_gemm<<<dim3(384), 512, 0, stream>>>(Xb, Wqb, Wkb, Wvb, RoTab, Qb, Kb, Vtb);
  flash_kernel<<<dim3(256), 256, 0, stream>>>(Qb, Kb, Vtb, Ao);
  out_gemm<<<dim3(512), 256, 0, stream>>>(Ao, Wob, out);
}

// Round 9
// 374.683 us; speedup vs baseline: 1.1742x; 1.0564x over previous
//
#include <hip/hip_runtime.h>
#include <stdint.h>

typedef unsigned short ushort_t;
typedef __attribute__((ext_vector_type(8))) __bf16 bf16x8;
typedef __attribute__((ext_vector_type(4))) float f32x4;

#define HIDDEN 2048
#define NHEADS 16
#define HDIM 128
#define SEQ 2048
#define BATCH 2
#define MROWS (BATCH*SEQ)

#define AS1 __attribute__((address_space(1)))
#define AS3 __attribute__((address_space(3)))

__device__ __forceinline__ ushort_t f2bf(float f) {
  uint32_t u = __float_as_uint(f);
  u += 0x7FFFu + ((u >> 16) & 1u);
  return (ushort_t)(u >> 16);
}
__device__ __forceinline__ float bf2f(ushort_t h) {
  return __uint_as_float((uint32_t)h << 16);
}

__device__ __forceinline__ f32x4 mfma16(bf16x8 a, bf16x8 b, f32x4 c) {
  return __builtin_amdgcn_mfma_f32_16x16x32_bf16(a, b, c, 0, 0, 0);
}

// ---------------- fp32 -> bf16 converts (+ RoPE table fill) ----------------
// RoTab[s*64+dl] = (cos, sin)(s * 10000^(-dl/64)) -- same formula as the R6-passing
// epilogue sincosf, so downstream math is bit-identical to the R6 pass.
__global__ void cvt_kernel(const float* __restrict__ in, ushort_t* __restrict__ out,
                           float2* __restrict__ rotab, int n4) {
  int i = blockIdx.x * blockDim.x + threadIdx.x;
  if (i < n4) {
    float4 v = ((const float4*)in)[i];
    uint32_t lo = (uint32_t)f2bf(v.x) | ((uint32_t)f2bf(v.y) << 16);
    uint32_t hi = (uint32_t)f2bf(v.z) | ((uint32_t)f2bf(v.w) << 16);
    ((uint2*)out)[i] = make_uint2(lo, hi);
  }
  if (i < SEQ * 64) {
    int s = i >> 6, dl = i & 63;
    float th = exp2f((float)dl * -0.2076205059304601f);
    float sn, cs;
    sincosf((float)s * th, &sn, &cs);
    rotab[i] = make_float2(cs, sn);
  }
}

__global__ void cvt4_kernel(const float* __restrict__ w0, const float* __restrict__ w1,
                            const float* __restrict__ w2, const float* __restrict__ w3,
                            ushort_t* __restrict__ o0, ushort_t* __restrict__ o1,
                            ushort_t* __restrict__ o2, ushort_t* __restrict__ o3) {
  int y = blockIdx.y;
  const float* in = (y == 0) ? w0 : (y == 1) ? w1 : (y == 2) ? w2 : w3;
  ushort_t* out = (y == 0) ? o0 : (y == 1) ? o1 : (y == 2) ? o2 : o3;
  int i = blockIdx.x * blockDim.x + threadIdx.x;
  float4 v = ((const float4*)in)[i];
  uint32_t lo = (uint32_t)f2bf(v.x) | ((uint32_t)f2bf(v.y) << 16);
  uint32_t hi = (uint32_t)f2bf(v.z) | ((uint32_t)f2bf(v.w) << 16);
  ((uint2*)out)[i] = make_uint2(lo, hi);
}

// ------- 128x128x2048 GEMM core (kept for out_gemm) -------
__device__ __forceinline__ void gemm128_core(const ushort_t* __restrict__ Ag,
                                             const ushort_t* __restrict__ Bg,
                                             ushort_t* As, ushort_t* Bs,  // each 2*4096
                                             f32x4 acc[4][4], int tid) {
  const int lane = tid & 63, wv = tid >> 6;
  const int r4 = lane >> 2;
  const int c8 = (((lane & 3) ^ ((r4 >> 1) & 3)) << 3);
  const int wm = (wv >> 1) * 64, wn = (wv & 1) * 64;
  const int mq = lane & 15, quad = lane >> 4;
  const int sw = (mq >> 1) & 3;

  auto stage = [&](int k0, int buf) {
#pragma unroll
    for (int cc = 0; cc < 2; ++cc) {
      int chunk = wv + cc * 4;
      const ushort_t* ga = Ag + (size_t)(chunk * 16 + r4) * HIDDEN + k0 + c8;
      const ushort_t* gb = Bg + (size_t)(chunk * 16 + r4) * HIDDEN + k0 + c8;
      __builtin_amdgcn_global_load_lds((AS1 void*)ga, (AS3 void*)(As + buf * 4096 + chunk * 512), 16, 0, 0);
      __builtin_amdgcn_global_load_lds((AS1 void*)gb, (AS3 void*)(Bs + buf * 4096 + chunk * 512), 16, 0, 0);
    }
  };

  stage(0, 0);
  __syncthreads();
#pragma unroll 1
  for (int k0 = 0; k0 < HIDDEN; k0 += 32) {
    const int cur = (k0 >> 5) & 1;
    if (k0 + 32 < HIDDEN) stage(k0 + 32, cur ^ 1);
    const ushort_t* A = As + cur * 4096;
    const ushort_t* B = Bs + cur * 4096;
    bf16x8 a[4], b[4];
#pragma unroll
    for (int i = 0; i < 4; ++i)
      a[i] = *(const bf16x8*)(A + (wm + i * 16 + mq) * 32 + ((quad ^ sw) << 3));
#pragma unroll
    for (int j = 0; j < 4; ++j)
      b[j] = *(const bf16x8*)(B + (wn + j * 16 + mq) * 32 + ((quad ^ sw) << 3));
#pragma unroll
    for (int i = 0; i < 4; ++i)
#pragma unroll
      for (int j = 0; j < 4; ++j)
        acc[i][j] = mfma16(a[i], b[j], acc[i][j]);
    __syncthreads();
  }
}

// ================= fused QKV projection: 256x256 tile, 8-wave, 8-phase =================
// (R2/R5/R8-measured core: ~129-132 us, MfmaUtil 32%, bank-conflict ~0. Proven pass.)
// RoPE fused into the Q/K epilogue via the precomputed RoTab (one 8B L2 load per (a,r)).

#define QKV_PHASE_MFMA(MH, NH, BB)                                                  \
  __builtin_amdgcn_s_barrier();                                                     \
  asm volatile("s_waitcnt lgkmcnt(0)" ::: "memory");                                \
  __builtin_amdgcn_s_setprio(1);                                                    \
  _Pragma("unroll") for (int f_ = 0; f_ < 4; ++f_)                                  \
  _Pragma("unroll") for (int n_ = 0; n_ < 2; ++n_)                                  \
  _Pragma("unroll") for (int kk_ = 0; kk_ < 2; ++kk_)                               \
    acc[(MH)*4+f_][(NH)*2+n_] =                                                     \
      mfma16(af[f_*2+kk_], BB[n_*2+kk_], acc[(MH)*4+f_][(NH)*2+n_]);                \
  __builtin_amdgcn_s_setprio(0);

#define QKV_TILE(CB, NB, KT)                                                        \
  {                                                                                 \
    const ushort_t* A_ = lds_q + (CB);                                              \
    const ushort_t* B_ = lds_q + (CB) + 16384;                                      \
    _Pragma("unroll") for (int u = 0; u < 8; ++u) af[u] = *(const bf16x8*)(A_ + aoff[u]); \
    _Pragma("unroll") for (int u = 0; u < 4; ++u) b0r[u] = *(const bf16x8*)(B_ + boff[u]); \
    stageA((KT), 0, (NB));                                                          \
    QKV_PHASE_MFMA(0, 0, b0r)                                                       \
    asm volatile("s_waitcnt vmcnt(4)" ::: "memory");                                \
    __builtin_amdgcn_s_barrier();                                                   \
    _Pragma("unroll") for (int u = 0; u < 4; ++u) b1r[u] = *(const bf16x8*)(B_ + 8192 + boff[u]); \
    stageB((KT), 0, (NB));                                                          \
    QKV_PHASE_MFMA(0, 1, b1r)                                                       \
    asm volatile("s_waitcnt vmcnt(4)" ::: "memory");                                \
    __builtin_amdgcn_s_barrier();                                                   \
    _Pragma("unroll") for (int u = 0; u < 8; ++u) af[u] = *(const bf16x8*)(A_ + 8192 + aoff[u]); \
    stageB((KT), 1, (NB));                                                          \
    QKV_PHASE_MFMA(1, 1, b1r)                                                       \
    __builtin_amdgcn_s_barrier();                                                   \
    stageA((KT), 1, (NB));                                                          \
    QKV_PHASE_MFMA(1, 0, b0r)                                                       \
    asm volatile("s_waitcnt vmcnt(4)" ::: "memory");                                \
    __builtin_amdgcn_s_barrier();                                                   \
  }

#define QKV_TAIL(CB)                                                                \
  {                                                                                 \
    const ushort_t* A_ = lds_q + (CB);                                              \
    const ushort_t* B_ = lds_q + (CB) + 16384;                                      \
    _Pragma("unroll") for (int u = 0; u < 8; ++u) af[u] = *(const bf16x8*)(A_ + aoff[u]); \
    _Pragma("unroll") for (int u = 0; u < 4; ++u) b0r[u] = *(const bf16x8*)(B_ + boff[u]); \
    QKV_PHASE_MFMA(0, 0, b0r)                                                       \
    asm volatile("s_waitcnt vmcnt(2)" ::: "memory");                                \
    __builtin_amdgcn_s_barrier();                                                   \
    _Pragma("unroll") for (int u = 0; u < 4; ++u) b1r[u] = *(const bf16x8*)(B_ + 8192 + boff[u]); \
    QKV_PHASE_MFMA(0, 1, b1r)                                                       \
    asm volatile("s_waitcnt vmcnt(0)" ::: "memory");                                \
    __builtin_amdgcn_s_barrier();                                                   \
    _Pragma("unroll") for (int u = 0; u < 8; ++u) af[u] = *(const bf16x8*)(A_ + 8192 + aoff[u]); \
    QKV_PHASE_MFMA(1, 1, b1r)                                                       \
    __builtin_amdgcn_s_barrier();                                                   \
    QKV_PHASE_MFMA(1, 0, b0r)                                                       \
  }

__global__ __launch_bounds__(512, 2) void qkv_gemm(const ushort_t* __restrict__ X,
                                                   const ushort_t* __restrict__ Wq,
                                                   const ushort_t* __restrict__ Wk,
                                                   const ushort_t* __restrict__ Wv,
                                                   const float2* __restrict__ RoTab,
                                                   ushort_t* __restrict__ Q,
                                                   ushort_t* __restrict__ K,
                                                   ushort_t* __restrict__ Vt) {
  __shared__ __align__(16) ushort_t lds_q[65536];   // 128 KiB

  const int tid = threadIdx.x, lane = tid & 63, wv = tid >> 6;
  const int wr = wv >> 2, wc = wv & 3;
  const int mq = lane & 15, quad = lane >> 4;
  const int lr = lane >> 3;
  const int csw = ((lane & 7) ^ (lr & 7)) * 8;      // pre-swizzled source col (elems)

  // block mapping: 384 blocks, XCD gets 3 consecutive N-panels (3 MB, L2-resident)
  const int lin = blockIdx.x;
  const int xcd = lin & 7, s = lin >> 3;            // s in [0,48)
  const int by = xcd * 3 + (s % 3);                 // 24 N-tiles
  const int bx = s / 3;                             // 16 M-tiles
  const int m0 = bx * 256;
  const int nglob = by * 256;
  const int which = nglob >> 11;
  const int n0 = nglob & 2047;
  const ushort_t* Ag = X + (size_t)m0 * HIDDEN;
  const ushort_t* Bg = ((which == 0) ? Wq : (which == 1) ? Wk : Wv) + (size_t)n0 * HIDDEN;

  // LDS read offsets (elems). Fragment interleave: wave wr owns M rows {f*32 + wr*16 + mq},
  // wave wc owns N cols {n*64 + wc*16 + mq} -> phase (mh,nh) touches exactly half (mh)/(nh).
  int aoff[8], boff[4];
#pragma unroll
  for (int f = 0; f < 4; ++f)
#pragma unroll
    for (int kk = 0; kk < 2; ++kk)
      aoff[f * 2 + kk] = (f * 32 + wr * 16 + mq) * 64 + (((kk * 4 + quad) ^ (mq & 7)) * 8);
#pragma unroll
  for (int n = 0; n < 2; ++n)
#pragma unroll
    for (int kk = 0; kk < 2; ++kk)
      boff[n * 2 + kk] = (n * 64 + wc * 16 + mq) * 64 + (((kk * 4 + quad) ^ (mq & 7)) * 8);

  auto stageA = [&](int kt, int half, int nb) {
#pragma unroll
    for (int i = 0; i < 2; ++i) {
      int seg = wv + i * 8;
      const ushort_t* src = Ag + (size_t)(half * 128 + seg * 8 + lr) * HIDDEN + kt * 64 + csw;
      __builtin_amdgcn_global_load_lds((AS1 void*)src,
                                       (AS3 void*)(lds_q + nb + half * 8192 + seg * 512), 16, 0, 0);
    }
  };
  auto stageB = [&](int kt, int half, int nb) {
#pragma unroll
    for (int i = 0; i < 2; ++i) {
      int seg = wv + i * 8;
      const ushort_t* src = Bg + (size_t)(half * 128 + seg * 8 + lr) * HIDDEN + kt * 64 + csw;
      __builtin_amdgcn_global_load_lds((AS1 void*)src,
                                       (AS3 void*)(lds_q + nb + 16384 + half * 8192 + seg * 512), 16, 0, 0);
    }
  };

  f32x4 acc[8][4];
  const f32x4 zf = {0.f, 0.f, 0.f, 0.f};
#pragma unroll
  for (int i = 0; i < 8; ++i)
#pragma unroll
    for (int j = 0; j < 4; ++j) acc[i][j] = zf;

  bf16x8 af[8], b0r[4], b1r[4];

  // prologue: tile 0, issue order == consumption order (A0,B0,B1,A1)
  stageA(0, 0, 0);
  stageB(0, 0, 0);
  stageB(0, 1, 0);
  stageA(0, 1, 0);
  __syncthreads();

#pragma unroll 1
  for (int tp = 0; tp < 15; ++tp) {
    QKV_TILE(0, 32768, 2 * tp + 1)
    QKV_TILE(32768, 0, 2 * tp + 2)
  }
  QKV_TILE(0, 32768, 31)
  QKV_TAIL(32768)

  // -------- epilogue --------
  // acc[a][c]: M row = m0 + (a>>2)*128 + (a&3)*32 + wr*16 + quad*4 + r
  //            N col = n0 + (c>>1)*128 + (c&1)*64 + wc*16 + mq
  // Q/K: columns (c=2cp, c=2cp+1) are (d_low, d_low+64) of the SAME rows with
  // d_low = wc*16+mq < 64 -> RoPE in-register (fp32) via RoTab, single bf16 rounding.
  if (which != 2) {
    ushort_t* dst = (which == 0) ? Q : K;
    const float qscale = (which == 0) ? 0.08838834764831845f : 1.0f;
    const int dl = wc * 16 + mq;                         // d_low in [0,64)
#pragma unroll
    for (int a = 0; a < 8; ++a) {
#pragma unroll
      for (int r = 0; r < 4; ++r) {
        int mrow = m0 + (a >> 2) * 128 + (a & 3) * 32 + wr * 16 + quad * 4 + r;
        int bb = mrow >> 11, sq = mrow & (SEQ - 1);
        float2 t = RoTab[(sq << 6) + dl];
        float cs = t.x, sn = t.y;
#pragma unroll
        for (int cp = 0; cp < 2; ++cp) {
          float lo = acc[a][cp * 2][r], hi = acc[a][cp * 2 + 1][r];
          float nlo = (lo * cs - hi * sn) * qscale;
          float nhi = (hi * cs + lo * sn) * qscale;
          int ocol = n0 + cp * 128 + dl;                 // low-half column
          int hh = ocol >> 7;
          size_t base = ((size_t)(bb * NHEADS + hh) * SEQ + sq) * HDIM + dl;
          dst[base]      = f2bf(nlo);
          dst[base + 64] = f2bf(nhi);
        }
      }
    }
  } else {
    // V: transpose 256x256 through the full staging LDS -> coalesced uint4 stores to Vt
    __syncthreads();
#pragma unroll
    for (int a = 0; a < 8; ++a)
#pragma unroll
      for (int c4 = 0; c4 < 4; ++c4) {
        int cc = (c4 >> 1) * 128 + (c4 & 1) * 64 + wc * 16 + mq;
        int mb = (a >> 2) * 128 + (a & 3) * 32 + wr * 16 + quad * 4;
        uint32_t lo = (uint32_t)f2bf(acc[a][c4][0]) | ((uint32_t)f2bf(acc[a][c4][1]) << 16);
        uint32_t hi = (uint32_t)f2bf(acc[a][c4][2]) | ((uint32_t)f2bf(acc[a][c4][3]) << 16);
        *(uint2*)(lds_q + cc * 256 + (mb ^ ((cc & 7) * 8))) = make_uint2(lo, hi);
      }
    __syncthreads();
    const int bb = m0 >> 11, sq0 = m0 & (SEQ - 1);
#pragma unroll
    for (int it = 0; it < 16; ++it) {
      int cc = it * 16 + (tid >> 5);
      int sc = tid & 31;
      uint4 v = *(const uint4*)(lds_q + cc * 256 + ((sc ^ (cc & 7)) * 8));
      int hh = (n0 + cc) >> 7, d = (n0 + cc) & (HDIM - 1);
      *(uint4*)(Vt + ((size_t)(bb * NHEADS + hh) * HDIM + d) * SEQ + sq0 + sc * 8) = v;
    }
  }
}

// ---- causal flash attention: CONCURRENT shared-prefix pair (T, 15-T) ----
// 512 threads = 2 groups x 4 waves. The short tile's key range is a strict PREFIX of
// the long tile's -> both groups consume the SAME staged K/V tiles. Group g owns tile
// T_g with private m/l/oacc/sP; all 8 waves co-stage; short group predicates off after
// its nsteps (wave-uniform branch; barrier outside). LDS 96KB: sK 2x16K | sV 2x16K |
// sP[2] 2x16K. 2 waves/SIMD -> one group's MFMA overlaps the other's softmax VALU.
// Per-tile math/order identical to the R8-passing kernel -> same absmax.
__global__ __launch_bounds__(512, 1) void flash_kernel(const ushort_t* __restrict__ Q,
                                                       const ushort_t* __restrict__ K,
                                                       const ushort_t* __restrict__ Vt,
                                                       ushort_t* __restrict__ Ao) {
  __shared__ __align__(16) ushort_t smem[49152];       // 96 KB
  // layout (ushorts): sK0 @0, sK1 @8192, sV0 @16384, sV1 @24576, sP(grp) @32768+grp*8192
  const int tid = threadIdx.x, lane = tid & 63, wv = tid >> 6;
  const int grp = wv >> 2, wg = wv & 3;
  const int lq = lane & 15, quad = lane >> 4;
  const int lin = blockIdx.x;
  const int xcd = lin & 7, slot = lin >> 3;
  const int bh = xcd * 4 + (slot & 3);
  const int p = slot >> 2;                             // 0..7
  const int T = grp ? (15 - p) : p;
  const int nsteps = 2 * T + 2;
  const int jmax = 32 - 2 * p;                         // == long group's nsteps
  ushort_t* sKb0 = smem;
  ushort_t* sKb1 = smem + 8192;
  ushort_t* sVb0 = smem + 16384;
  ushort_t* sVb1 = smem + 24576;
  ushort_t* sP   = smem + 32768 + grp * 8192;          // group-private P^T [q][key]

  const ushort_t* Qb = Q + (size_t)bh * SEQ * HDIM;
  const ushort_t* Kb = K + (size_t)bh * SEQ * HDIM;
  const ushort_t* Vb = Vt + (size_t)bh * HDIM * SEQ;
  const int b = bh >> 4, h = bh & 15;

  auto stageK = [&](int j, ushort_t* dst) {
    int rr = lane >> 4, g = lane & 15;
#pragma unroll
    for (int t = 0; t < 2; ++t) {
      int chunk = wv * 2 + t;
      int row = chunk * 4 + rr;
      int gs = (g ^ (row & 7)) * 8;
      __builtin_amdgcn_global_load_lds((AS1 void*)(Kb + (size_t)(j * 64 + row) * HDIM + gs),
                                       (AS3 void*)(dst + chunk * 512), 16, 0, 0);
    }
  };
  auto stageV = [&](int j, ushort_t* dst) {
    int rr = lane >> 3, g = lane & 7;
#pragma unroll
    for (int t = 0; t < 2; ++t) {
      int chunk = wv * 2 + t;
      int row = chunk * 8 + rr;
      int gs = (g ^ (row & 7)) * 8;
      __builtin_amdgcn_global_load_lds((AS1 void*)(Vb + (size_t)row * SEQ + j * 64 + gs),
                                       (AS3 void*)(dst + chunk * 512), 16, 0, 0);
    }
  };

  const f32x4 zf = {0.f, 0.f, 0.f, 0.f};

  bf16x8 qf[2][4];
#pragma unroll
  for (int n = 0; n < 2; ++n)
#pragma unroll
    for (int kt = 0; kt < 4; ++kt)
      qf[n][kt] = *(const bf16x8*)(Qb + (size_t)(T * 128 + wg * 32 + n * 16 + lq) * HDIM +
                                   kt * 32 + quad * 8);

  float m_i[2] = {-1e30f, -1e30f}, l_i[2] = {0.f, 0.f};
  f32x4 oacc[8][2];
#pragma unroll
  for (int m = 0; m < 8; ++m)
#pragma unroll
    for (int n = 0; n < 2; ++n) oacc[m][n] = zf;

  stageK(0, sKb0);
  stageV(0, sVb0);
  __syncthreads();

#pragma unroll 1
  for (int j = 0; j < jmax; ++j) {
    const int cur = j & 1;
    const ushort_t* sKc = cur ? sKb1 : sKb0;
    const ushort_t* sVc = cur ? sVb1 : sVb0;
    if (j + 1 < jmax) {
      stageK(j + 1, cur ? sKb0 : sKb1);
      stageV(j + 1, cur ? sVb0 : sVb1);
    }

    if (j < nsteps) {
      f32x4 sacc[4][2];
#pragma unroll
      for (int m = 0; m < 4; ++m)
#pragma unroll
        for (int n = 0; n < 2; ++n) sacc[m][n] = zf;
#pragma unroll
      for (int kt = 0; kt < 4; ++kt) {
        bf16x8 kf[4];
#pragma unroll
        for (int m = 0; m < 4; ++m) {
          int row = m * 16 + lq;
          kf[m] = *(const bf16x8*)(sKc + row * 128 + (((kt * 4 + quad) ^ (row & 7)) * 8));
        }
#pragma unroll
        for (int m = 0; m < 4; ++m)
#pragma unroll
          for (int n = 0; n < 2; ++n)
            sacc[m][n] = mfma16(kf[m], qf[n][kt], sacc[m][n]);
      }

      const bool diag = (j >= 2 * T);
#pragma unroll
      for (int n = 0; n < 2; ++n) {
        const int qr = wg * 32 + n * 16 + lq;
        if (diag) {
          const int rowg = T * 128 + qr;
#pragma unroll
          for (int m = 0; m < 4; ++m)
#pragma unroll
            for (int r = 0; r < 4; ++r) {
              int key = j * 64 + m * 16 + quad * 4 + r;
              if (key > rowg) sacc[m][n][r] = -1e30f;
            }
        }
        float rm = -1e30f;
#pragma unroll
        for (int m = 0; m < 4; ++m)
#pragma unroll
          for (int r = 0; r < 4; ++r) rm = fmaxf(rm, sacc[m][n][r]);
        rm = fmaxf(rm, __shfl_xor(rm, 16, 64));
        rm = fmaxf(rm, __shfl_xor(rm, 32, 64));
        float mnew = fmaxf(m_i[n], rm);
        float alpha = __expf(m_i[n] - mnew);
        m_i[n] = mnew;
        float rs = 0.f;
#pragma unroll
        for (int m = 0; m < 4; ++m)
#pragma unroll
          for (int r = 0; r < 4; ++r) {
            float pz = __expf(sacc[m][n][r] - mnew);
            sacc[m][n][r] = pz;
            rs += pz;
          }
        rs += __shfl_xor(rs, 16, 64);
        rs += __shfl_xor(rs, 32, 64);
        l_i[n] = l_i[n] * alpha + rs;
#pragma unroll
        for (int m = 0; m < 8; ++m)
#pragma unroll
          for (int r = 0; r < 4; ++r) oacc[m][n][r] *= alpha;
#pragma unroll
        for (int m = 0; m < 4; ++m) {
          uint32_t lo = (uint32_t)f2bf(sacc[m][n][0]) | ((uint32_t)f2bf(sacc[m][n][1]) << 16);
          uint32_t hi = (uint32_t)f2bf(sacc[m][n][2]) | ((uint32_t)f2bf(sacc[m][n][3]) << 16);
          int gw = m * 2 + (quad >> 1);
          *(uint2*)(sP + qr * 64 + ((gw ^ (qr & 7)) * 8) + (quad & 1) * 4) = make_uint2(lo, hi);
        }
      }

#pragma unroll
      for (int kt = 0; kt < 2; ++kt) {
        bf16x8 pf[2];
#pragma unroll
        for (int n = 0; n < 2; ++n) {
          int qr = wg * 32 + n * 16 + lq;
          pf[n] = *(const bf16x8*)(sP + qr * 64 + (((kt * 4 + quad) ^ (qr & 7)) * 8));
        }
#pragma unroll
        for (int m = 0; m < 8; ++m) {
          int d = m * 16 + lq;
          bf16x8 vf = *(const bf16x8*)(sVc + d * 64 + (((kt * 4 + quad) ^ (d & 7)) * 8));
#pragma unroll
          for (int n = 0; n < 2; ++n)
            oacc[m][n] = mfma16(vf, pf[n], oacc[m][n]);
        }
      }
    }

    __syncthreads();
  }

  // epilogue: pack each group's 128x128 tile into its sO half (aliases sK/sV), store.
  ushort_t* sO = smem + grp * 16384;
  float inv0 = 1.f / l_i[0], inv1 = 1.f / l_i[1];
#pragma unroll
  for (int n = 0; n < 2; ++n) {
    float inv = n ? inv1 : inv0;
    int qr = wg * 32 + n * 16 + lq;
#pragma unroll
    for (int m = 0; m < 8; ++m) {
      uint32_t lo = (uint32_t)f2bf(oacc[m][n][0] * inv) | ((uint32_t)f2bf(oacc[m][n][1] * inv) << 16);
      uint32_t hi = (uint32_t)f2bf(oacc[m][n][2] * inv) | ((uint32_t)f2bf(oacc[m][n][3] * inv) << 16);
      int gw = m * 2 + (quad >> 1);
      *(uint2*)(sO + qr * 128 + ((gw ^ (qr & 7)) * 8) + (quad & 1) * 4) = make_uint2(lo, hi);
    }
  }
  __syncthreads();
  {
    const int ltid = tid & 255;
#pragma unroll
    for (int it = 0; it < 8; ++it) {
      int qr = it * 16 + (ltid >> 4);
      int g = ltid & 15;
      uint4 v = *(const uint4*)(sO + qr * 128 + ((g ^ (qr & 7)) * 8));
      *(uint4*)(Ao + ((size_t)(b * SEQ + T * 128 + qr)) * (NHEADS * HDIM) + h * HDIM + g * 8) = v;
    }
  }
}

// ---------------- output projection (fp32 out, XCD-swizzled) ----------------
__global__ __launch_bounds__(256) void out_gemm(const ushort_t* __restrict__ Ain,
                                                const ushort_t* __restrict__ Wo,
                                                float* __restrict__ Y) {
  __shared__ __align__(16) ushort_t As[2][128 * 32];
  __shared__ __align__(16) ushort_t Bs[2][128 * 32];
  const int tid = threadIdx.x;
  const int lin = blockIdx.x;
  const int xcd = lin & 7, s = lin >> 3;
  const int by = xcd + 8 * (s & 1);
  const int bx = s >> 1;
  const int m0 = bx * 128;
  const int n0 = by * 128;

  f32x4 acc[4][4];
  const f32x4 zf = {0.f, 0.f, 0.f, 0.f};
#pragma unroll
  for (int i = 0; i < 4; ++i)
#pragma unroll
    for (int j = 0; j < 4; ++j) acc[i][j] = zf;

  gemm128_core(Ain + (size_t)m0 * HIDDEN, Wo + (size_t)n0 * HIDDEN, &As[0][0], &Bs[0][0], acc, tid);

  const int lane = tid & 63, wv = tid >> 6;
  const int wm = (wv >> 1) * 64, wn = (wv & 1) * 64;
  const int mq = lane & 15, quad = lane >> 4;
#pragma unroll
  for (int i = 0; i < 4; ++i)
#pragma unroll
    for (int j = 0; j < 4; ++j)
#pragma unroll
      for (int r = 0; r < 4; ++r) {
        int m = m0 + wm + i * 16 + quad * 4 + r;
        int o = n0 + wn + j * 16 + mq;
        Y[(size_t)m * HIDDEN + o] = acc[i][j][r];
      }
}

extern "C" void kernel_launch(void* const* d_in, const int* in_sizes, int n_in,
                              void* d_out, int out_size, void* d_ws, size_t ws_size,
                              hipStream_t stream) {
  const float* hs = (const float*)d_in[0];
  const float* Wq = (const float*)d_in[1];
  const float* Wk = (const float*)d_in[2];
  const float* Wv = (const float*)d_in[3];
  const float* Wo = (const float*)d_in[4];
  float* out = (float*)d_out;

  ushort_t* ws  = (ushort_t*)d_ws;
  ushort_t* Xb  = ws;
  ushort_t* Wqb = Xb  + (size_t)MROWS * HIDDEN;
  ushort_t* Wkb = Wqb + (size_t)HIDDEN * HIDDEN;
  ushort_t* Wvb = Wkb + (size_t)HIDDEN * HIDDEN;
  ushort_t* Wob = Wvb + (size_t)HIDDEN * HIDDEN;
  ushort_t* Qb  = Wob + (size_t)HIDDEN * HIDDEN;
  ushort_t* Kb  = Qb  + (size_t)MROWS * HIDDEN;
  ushort_t* Vtb = Kb  + (size_t)MROWS * HIDDEN;
  ushort_t* Ao  = Vtb + (size_t)MROWS * HIDDEN;
  float2*   RoTab = (float2*)(Ao + (size_t)MROWS * HIDDEN);

  cvt_kernel<<<(MROWS * HIDDEN / 4) / 256, 256, 0, stream>>>(hs, Xb, RoTab, MROWS * HIDDEN / 4);
  cvt4_kernel<<<dim3((HIDDEN * HIDDEN / 4) / 256, 4), 256, 0, stream>>>(
      Wq, Wk, Wv, Wo, Wqb, Wkb, Wvb, Wob);

  qkv_gemm<<<dim3(384), 512, 0, stream>>>(Xb, Wqb, Wkb, Wvb, RoTab, Qb, Kb, Vtb);
  flash_kernel<<<dim3(256), 512, 0, stream>>>(Qb, Kb, Vtb, Ao);
  out_gemm<<<dim3(512), 256, 0, stream>>>(Ao, Wob, out);
}